// Round 3
// baseline (208.500 us; speedup 1.0000x reference)
//
#include <hip/hip_runtime.h>
#include <math.h>

constexpr int B = 2;
constexpr int S = 2048;
constexpr int DMODEL = 1024;
constexpr int H = 16;
constexpr int M_TOT = B * S;                     // 4096
constexpr size_t MAT = (size_t)B * S * DMODEL;   // 4,194,304 elements

typedef __attribute__((ext_vector_type(8))) __bf16 bf16x8;
typedef __attribute__((ext_vector_type(4))) float f32x4;

#define GLOAD16(g, l) __builtin_amdgcn_global_load_lds( \
    (const __attribute__((address_space(1))) void*)(g), \
    (__attribute__((address_space(3))) void*)(l), 16, 0, 0)

__device__ __forceinline__ float bf2f(__bf16 v) { return (float)v; }
__device__ __forceinline__ __bf16 f2bf(float v) { return (__bf16)v; }
__device__ __forceinline__ float silu(float z) { return z / (1.0f + expf(-z)); }

// ---------------------------------------------------------------------------
// Prep: x fp32 -> bf16 (8 elems / thread)
// ---------------------------------------------------------------------------
__global__ __launch_bounds__(256) void cvt_x_kernel(const float* __restrict__ x,
                                                    __bf16* __restrict__ xb)
{
    const size_t p = (size_t)blockIdx.x * 256 + threadIdx.x;  // group of 8
    const float4 a = reinterpret_cast<const float4*>(x)[2 * p];
    const float4 b = reinterpret_cast<const float4*>(x)[2 * p + 1];
    bf16x8 o;
    o[0] = f2bf(a.x); o[1] = f2bf(a.y); o[2] = f2bf(a.z); o[3] = f2bf(a.w);
    o[4] = f2bf(b.x); o[5] = f2bf(b.y); o[6] = f2bf(b.z); o[7] = f2bf(b.w);
    reinterpret_cast<bf16x8*>(xb)[p] = o;
}

// ---------------------------------------------------------------------------
// Prep: transpose + convert weights. z = 0..3 -> Wq,Wk,Wv,Wg into wqkvg_t
// (row n_global = z*1024 + n, col k). z = 4 -> Wo into wo_t.
// ---------------------------------------------------------------------------
__global__ __launch_bounds__(256) void transpose_w_kernel(
    const float* Wq, const float* Wk, const float* Wv, const float* Wg,
    const float* Wo, __bf16* __restrict__ wqkvg_t, __bf16* __restrict__ wo_t)
{
    __shared__ float tile[32][33];
    const int z = blockIdx.z;
    const float* W = (z == 0) ? Wq : (z == 1) ? Wk : (z == 2) ? Wv
                    : (z == 3) ? Wg : Wo;
    const int n0 = blockIdx.x * 32, k0 = blockIdx.y * 32;
    const int tx = threadIdx.x & 31, ty = threadIdx.x >> 5;  // 32 x 8

    #pragma unroll
    for (int i = 0; i < 32; i += 8)
        tile[ty + i][tx] = W[(size_t)(k0 + ty + i) * DMODEL + n0 + tx];
    __syncthreads();
    #pragma unroll
    for (int i = 0; i < 32; i += 8) {
        const int n = n0 + ty + i, kk = k0 + tx;
        const __bf16 val = f2bf(tile[tx][ty + i]);
        if (z < 4) wqkvg_t[((size_t)z * 1024 + n) * DMODEL + kk] = val;
        else       wo_t[(size_t)n * DMODEL + kk] = val;
    }
}

__global__ __launch_bounds__(256) void pack_bias_kernel(
    const float* bq, const float* bk, const float* bv, const float* bg,
    float* __restrict__ bqkvg)
{
    const int i = blockIdx.x * 256 + threadIdx.x;  // 0..4095
    const float* src = ((i >> 10) == 0) ? bq : ((i >> 10) == 1) ? bk
                      : ((i >> 10) == 2) ? bv : bg;
    bqkvg[i] = src[i & 1023];
}

// ---------------------------------------------------------------------------
// MFMA GEMM: C = A(MxK,bf16) @ Bt(NxK,bf16)^T + bias.
// 128x128 tile, BK=32, 256 threads (4 waves 2x2 of 64x64), global_load_lds.
// OUTMODE 0: bf16 out split into 4 buffers of width 1024 by col/1024.
// OUTMODE 1: f32 out, width N.
// ---------------------------------------------------------------------------
template <int OUTMODE>
__global__ __launch_bounds__(256) void gemm_mfma_kernel(
    const __bf16* __restrict__ A, const __bf16* __restrict__ Bt,
    const float* __restrict__ bias,
    __bf16* o0, __bf16* o1, __bf16* o2, __bf16* o3,
    float* fout, int M, int N, int K)
{
    __shared__ __bf16 a_lds[128 * 32];
    __shared__ __bf16 b_lds[128 * 32];

    const int t = threadIdx.x, wv = t >> 6, ln = t & 63;
    const int row0 = blockIdx.y * 128, col0 = blockIdx.x * 128;
    const int wr = (wv >> 1) * 64, wc = (wv & 1) * 64;
    const int lrow = ln & 15, lk8 = (ln >> 4) * 8;

    f32x4 acc[4][4] = {};

    for (int k0 = 0; k0 < K; k0 += 32) {
        __syncthreads();
        #pragma unroll
        for (int p = 0; p < 2; ++p) {
            const int ci = p * 256 + t;
            GLOAD16(A + (size_t)(row0 + (ci >> 2)) * K + k0 + (ci & 3) * 8,
                    (char*)a_lds + p * 4096 + wv * 1024);
            GLOAD16(Bt + (size_t)(col0 + (ci >> 2)) * K + k0 + (ci & 3) * 8,
                    (char*)b_lds + p * 4096 + wv * 1024);
        }
        __syncthreads();

        bf16x8 af[4], bf[4];
        #pragma unroll
        for (int mi = 0; mi < 4; ++mi)
            af[mi] = *reinterpret_cast<const bf16x8*>(
                &a_lds[(wr + mi * 16 + lrow) * 32 + lk8]);
        #pragma unroll
        for (int ni = 0; ni < 4; ++ni)
            bf[ni] = *reinterpret_cast<const bf16x8*>(
                &b_lds[(wc + ni * 16 + lrow) * 32 + lk8]);
        #pragma unroll
        for (int mi = 0; mi < 4; ++mi)
            #pragma unroll
            for (int ni = 0; ni < 4; ++ni)
                acc[mi][ni] = __builtin_amdgcn_mfma_f32_16x16x32_bf16(
                    af[mi], bf[ni], acc[mi][ni], 0, 0, 0);
    }

    if (OUTMODE == 0) {
        const int sel = col0 >> 10;
        __bf16* outp = (sel == 0) ? o0 : (sel == 1) ? o1 : (sel == 2) ? o2 : o3;
        #pragma unroll
        for (int mi = 0; mi < 4; ++mi) {
            #pragma unroll
            for (int ni = 0; ni < 4; ++ni) {
                const int cfull = col0 + wc + ni * 16 + (ln & 15);
                const float bs = bias[cfull];
                #pragma unroll
                for (int reg = 0; reg < 4; ++reg) {
                    const int r = row0 + wr + mi * 16 + (ln >> 4) * 4 + reg;
                    outp[(size_t)r * 1024 + (cfull & 1023)] =
                        f2bf(acc[mi][ni][reg] + bs);
                }
            }
        }
    } else {
        #pragma unroll
        for (int mi = 0; mi < 4; ++mi) {
            #pragma unroll
            for (int ni = 0; ni < 4; ++ni) {
                const int c = col0 + wc + ni * 16 + (ln & 15);
                const float bs = bias[c];
                #pragma unroll
                for (int reg = 0; reg < 4; ++reg) {
                    const int r = row0 + wr + mi * 16 + (ln >> 4) * 4 + reg;
                    fout[(size_t)r * N + c] = acc[mi][ni][reg] + bs;
                }
            }
        }
    }
}

// ---------------------------------------------------------------------------
// xPos rotary on bf16 q (scale) and k (1/scale), in place.
// ---------------------------------------------------------------------------
__global__ __launch_bounds__(256) void rotary_bf16_kernel(__bf16* __restrict__ q,
                                                          __bf16* __restrict__ k)
{
    const int bs = blockIdx.x;
    const int s  = bs & (S - 1);
    const int h  = threadIdx.x >> 4;
    const int j  = threadIdx.x & 15;

    const float inv_freq = powf(10000.0f, -(float)j / 16.0f);
    const float freq = (float)s * inv_freq;
    const float c  = cosf(freq);
    const float sn = sinf(freq);
    const float base = (2.0f * j + 0.4f * 32.0f) / (1.4f * 32.0f);
    const float p    = ((float)s - (float)(S / 2)) / 512.0f;
    const float sc   = powf(base, p);

    const size_t off = (size_t)bs * DMODEL + h * 64 + 2 * j;

    const float q0 = bf2f(q[off]), q1 = bf2f(q[off + 1]);
    q[off]     = f2bf((q0 * c - q1 * sn) * sc);
    q[off + 1] = f2bf((q1 * c + q0 * sn) * sc);

    const float isc = 1.0f / sc;
    const float k0 = bf2f(k[off]), k1 = bf2f(k[off + 1]);
    k[off]     = f2bf((k0 * c - k1 * sn) * isc);
    k[off + 1] = f2bf((k1 * c + k0 * sn) * isc);
}

// ---------------------------------------------------------------------------
// Transpose V per (b,h): vb[b*S+s][h*64+d] -> vt[(b*16+h)*64+d][s]
// ---------------------------------------------------------------------------
__global__ __launch_bounds__(256) void transpose_v_kernel(
    const __bf16* __restrict__ vb, __bf16* __restrict__ vt)
{
    __shared__ __bf16 tile[64][72];
    const int stile = blockIdx.x;   // 0..31
    const int h = blockIdx.y, b = blockIdx.z;
    const int t = threadIdx.x;
    #pragma unroll
    for (int p = 0; p < 2; ++p) {
        const int ci = p * 256 + t;
        const int r = ci >> 3, c8 = (ci & 7) * 8;   // r = s_loc, c8 = d base
        *reinterpret_cast<bf16x8*>(&tile[r][c8]) =
            *reinterpret_cast<const bf16x8*>(
                &vb[(size_t)(b * S + stile * 64 + r) * DMODEL + h * 64 + c8]);
    }
    __syncthreads();
    #pragma unroll
    for (int p = 0; p < 2; ++p) {
        const int ci = p * 256 + t;
        const int d = ci >> 3, s8 = (ci & 7) * 8;
        bf16x8 o;
        #pragma unroll
        for (int w = 0; w < 8; ++w) o[w] = tile[s8 + w][d];
        *reinterpret_cast<bf16x8*>(
            &vt[((size_t)(b * 16 + h) * 64 + d) * 2048 + stile * 64 + s8]) = o;
    }
}

// ---------------------------------------------------------------------------
// Retention via MFMA, split-j balanced.
// Job jb per (b,h): jb<32 -> st=jb, j-tiles [0, min(st,15)];
//                   jb>=32 -> st=jb-16, j-tiles [16, st].
// Max 16 iterations per block. Partials scaled by invn, atomicAdd into ret.
// S^T = mfma(K,Q) so P is written as packed b64 (transpose-on-write).
// All LDS tiles 64x128B with XOR swizzle (byte ^= (row&7)<<4).
// ---------------------------------------------------------------------------
__global__ __launch_bounds__(256) void retention_mfma_kernel(
    const __bf16* __restrict__ qg, const __bf16* __restrict__ kg,
    const __bf16* __restrict__ vtg, float* __restrict__ ret)
{
    __shared__ __bf16 q_lds[64 * 64];
    __shared__ __bf16 k_lds[64 * 64];
    __shared__ __bf16 vt_lds[64 * 64];
    __shared__ __bf16 p_lds[64 * 64];

    const int jb = blockIdx.x, h = blockIdx.y, b = blockIdx.z;
    int st, jlo, jhi;
    if (jb < 32) { st = jb; jlo = 0; jhi = (st < 16) ? st : 15; }
    else         { st = jb - 16; jlo = 16; jhi = st; }
    const int s0 = st * 64;
    const int t = threadIdx.x, wv = t >> 6, ln = t & 63;
    const int lrow = ln & 15, lk8 = (ln >> 4) * 8;

    const float gamma  = 1.0f - exp2f(-5.0f - (float)h);
    const float l2g    = log2f(gamma);
    const float ginv   = exp2f(-l2g);           // 1/gamma
    const float ginv16 = exp2f(-16.0f * l2g);   // gamma^-16
    const size_t base  = (size_t)b * S * DMODEL + h * 64;       // q,k row-major
    const size_t baset = (size_t)(b * 16 + h) * 64 * 2048;      // vt [d][s]

    // stage q tile (swizzled)
    #pragma unroll
    for (int p = 0; p < 2; ++p) {
        const int ci = p * 256 + t;
        const int r = ci >> 3, c8 = (ci & 7) * 8;
        *(bf16x8*)((char*)q_lds + r * 128 + ((c8 * 2) ^ ((r & 7) << 4))) =
            *reinterpret_cast<const bf16x8*>(
                &qg[base + (size_t)(s0 + r) * DMODEL + c8]);
    }

    f32x4 oacc[4] = {};
    const int dib = s0 + wv * 16 + (ln & 15) - ((ln >> 4) * 4);
    const int iloc = wv * 16 + (ln & 15);

    for (int jt = jlo; jt <= jhi; ++jt) {
        const int j0 = jt * 64;
        __syncthreads();
        // stage k (row-major) and vt (d-major), both swizzled
        #pragma unroll
        for (int p = 0; p < 2; ++p) {
            const int ci = p * 256 + t;
            const int r = ci >> 3, c8 = (ci & 7) * 8;
            const int off = r * 128 + ((c8 * 2) ^ ((r & 7) << 4));
            *(bf16x8*)((char*)k_lds + off) =
                *reinterpret_cast<const bf16x8*>(
                    &kg[base + (size_t)(j0 + r) * DMODEL + c8]);
            *(bf16x8*)((char*)vt_lds + off) =
                *reinterpret_cast<const bf16x8*>(
                    &vtg[baset + (size_t)r * 2048 + j0 + c8]);
        }
        __syncthreads();

        // S^T = K @ Q^T : lane holds D[j=(ln>>4)*4+reg + 16mi][i=iloc]
        f32x4 sacc[4] = {};
        #pragma unroll
        for (int ks = 0; ks < 2; ++ks) {
            const int qrow = wv * 16 + lrow;
            const bf16x8 qf = *(const bf16x8*)((char*)q_lds + qrow * 128 +
                (((ks * 32 + lk8) * 2) ^ ((qrow & 7) << 4)));
            #pragma unroll
            for (int mi = 0; mi < 4; ++mi) {
                const int krow = mi * 16 + lrow;
                const bf16x8 kf = *(const bf16x8*)((char*)k_lds + krow * 128 +
                    (((ks * 32 + lk8) * 2) ^ ((krow & 7) << 4)));
                sacc[mi] = __builtin_amdgcn_mfma_f32_16x16x32_bf16(
                    kf, qf, sacc[mi], 0, 0, 0);
            }
        }

        // decay + causal mask, pack P[i][j] 4-at-a-time (ds_write_b64)
        const int di0 = dib - j0;      // i - j at mi=0, reg=0
        float wmi = exp2f((float)di0 * l2g);
        const bool diag = (jt == st);
        #pragma unroll
        for (int mi = 0; mi < 4; ++mi) {
            float wr = wmi;
            ushort4 pk;
            unsigned short* pkp = (unsigned short*)&pk;
            #pragma unroll
            for (int reg = 0; reg < 4; ++reg) {
                float wgt = wr;
                if (diag && (di0 - 16 * mi - reg) < 0) wgt = 0.0f;
                const __bf16 pb = f2bf(sacc[mi][reg] * wgt);
                pkp[reg] = *(const unsigned short*)&pb;
                wr *= ginv;
            }
            const int jb8 = mi * 16 + (ln >> 4) * 4;
            *(ushort4*)((char*)p_lds + iloc * 128 +
                        ((jb8 * 2) ^ ((iloc & 7) << 4))) = pk;
            wmi *= ginv16;
        }

        // PV: oacc[nd] += P(16x64) @ V(64x64); P rows are wave-private
        #pragma unroll
        for (int ks = 0; ks < 2; ++ks) {
            const int prow = wv * 16 + lrow;
            const bf16x8 pf = *(const bf16x8*)((char*)p_lds + prow * 128 +
                (((ks * 32 + lk8) * 2) ^ ((prow & 7) << 4)));
            #pragma unroll
            for (int nd = 0; nd < 4; ++nd) {
                const int vrow = nd * 16 + lrow;
                const bf16x8 vf = *(const bf16x8*)((char*)vt_lds + vrow * 128 +
                    (((ks * 32 + lk8) * 2) ^ ((vrow & 7) << 4)));
                oacc[nd] = __builtin_amdgcn_mfma_f32_16x16x32_bf16(
                    pf, vf, oacc[nd], 0, 0, 0);
            }
        }
    }

    // scale by closed-form normalizer and accumulate
    const float sc5h = exp2f(5.0f + (float)h);
    #pragma unroll
    for (int reg = 0; reg < 4; ++reg) {
        const int i = s0 + wv * 16 + (ln >> 4) * 4 + reg;
        const float omg = 1.0f - exp2f((float)(i + 1) * l2g);
        const float invn = rsqrtf(omg * sc5h);
        #pragma unroll
        for (int nd = 0; nd < 4; ++nd)
            atomicAdd(&ret[base + (size_t)i * DMODEL + nd * 16 + (ln & 15)],
                      oacc[nd][reg] * invn);
    }
}

// ---------------------------------------------------------------------------
// GroupNorm stats, 2 stages.
// ---------------------------------------------------------------------------
__global__ __launch_bounds__(256) void gn_stats1_kernel(const float* __restrict__ ret,
                                                        float* __restrict__ part)
{
    const int sl = blockIdx.x;          // 0..15 slice of 128 rows
    const int bh = blockIdx.y;          // 0..31
    const int b = bh >> 4, h = bh & 15;
    const size_t rowbase = ((size_t)b * S + sl * 128) * DMODEL + h * 64;
    float sum = 0.0f, sq = 0.0f;
    #pragma unroll
    for (int it = 0; it < 8; ++it) {
        const int idx = it * 256 + threadIdx.x;  // float4 index
        const int row = idx >> 4;
        const int c4 = (idx & 15) * 4;
        const float4 v = *reinterpret_cast<const float4*>(
            &ret[rowbase + (size_t)row * DMODEL + c4]);
        sum += v.x + v.y + v.z + v.w;
        sq  += v.x * v.x + v.y * v.y + v.z * v.z + v.w * v.w;
    }
    #pragma unroll
    for (int o = 32; o > 0; o >>= 1) {
        sum += __shfl_down(sum, o, 64);
        sq  += __shfl_down(sq, o, 64);
    }
    __shared__ float rs[4], rq[4];
    const int wid = threadIdx.x >> 6, lane = threadIdx.x & 63;
    if (lane == 0) { rs[wid] = sum; rq[wid] = sq; }
    __syncthreads();
    if (threadIdx.x == 0) {
        part[(bh * 16 + sl) * 2 + 0] = rs[0] + rs[1] + rs[2] + rs[3];
        part[(bh * 16 + sl) * 2 + 1] = rq[0] + rq[1] + rq[2] + rq[3];
    }
}

__global__ __launch_bounds__(64) void gn_stats2_kernel(const float* __restrict__ part,
                                                       float* __restrict__ stats)
{
    const int bh = threadIdx.x;
    if (bh < 32) {
        float s = 0.0f, q2 = 0.0f;
        for (int i = 0; i < 16; ++i) {
            s  += part[(bh * 16 + i) * 2 + 0];
            q2 += part[(bh * 16 + i) * 2 + 1];
        }
        const float inv_n = 1.0f / (float)(S * 64);
        const float mean = s * inv_n;
        const float var  = q2 * inv_n - mean * mean;
        stats[bh * 2 + 0] = mean;
        stats[bh * 2 + 1] = rsqrtf(var + 1e-5f);
    }
}

// ---------------------------------------------------------------------------
// y = ((ret - mean) * rstd * gn_w[h] + gn_b[h]) * silu(g), bf16 out.
// ---------------------------------------------------------------------------
__global__ __launch_bounds__(256) void gn_apply_kernel(
    const float* __restrict__ ret, const __bf16* __restrict__ g,
    __bf16* __restrict__ y, const float* __restrict__ stats,
    const float* __restrict__ gnw, const float* __restrict__ gnb)
{
    const size_t p = (size_t)blockIdx.x * 256 + threadIdx.x;  // group of 8
    const size_t el = p * 8;
    const int col = (int)(el & (DMODEL - 1));
    const int h   = col >> 6;
    const int b   = (int)(el >> 21);              // S*DMODEL = 2^21
    const int bh  = b * H + h;
    const float mean = stats[bh * 2 + 0];
    const float w    = stats[bh * 2 + 1] * gnw[h];
    const float bb   = gnb[h];

    const float4 r0 = reinterpret_cast<const float4*>(ret)[2 * p];
    const float4 r1 = reinterpret_cast<const float4*>(ret)[2 * p + 1];
    const bf16x8 gv = reinterpret_cast<const bf16x8*>(g)[p];
    bf16x8 o;
    o[0] = f2bf(((r0.x - mean) * w + bb) * silu(bf2f(gv[0])));
    o[1] = f2bf(((r0.y - mean) * w + bb) * silu(bf2f(gv[1])));
    o[2] = f2bf(((r0.z - mean) * w + bb) * silu(bf2f(gv[2])));
    o[3] = f2bf(((r0.w - mean) * w + bb) * silu(bf2f(gv[3])));
    o[4] = f2bf(((r1.x - mean) * w + bb) * silu(bf2f(gv[4])));
    o[5] = f2bf(((r1.y - mean) * w + bb) * silu(bf2f(gv[5])));
    o[6] = f2bf(((r1.z - mean) * w + bb) * silu(bf2f(gv[6])));
    o[7] = f2bf(((r1.w - mean) * w + bb) * silu(bf2f(gv[7])));
    reinterpret_cast<bf16x8*>(y)[p] = o;
}

// ---------------------------------------------------------------------------
extern "C" void kernel_launch(void* const* d_in, const int* in_sizes, int n_in,
                              void* d_out, int out_size, void* d_ws, size_t ws_size,
                              hipStream_t stream)
{
    const float* x   = (const float*)d_in[0];
    const float* Wq  = (const float*)d_in[1];
    const float* bq  = (const float*)d_in[2];
    const float* Wk  = (const float*)d_in[3];
    const float* bk  = (const float*)d_in[4];
    const float* Wv  = (const float*)d_in[5];
    const float* bv  = (const float*)d_in[6];
    const float* Wg  = (const float*)d_in[7];
    const float* bg  = (const float*)d_in[8];
    const float* Wo  = (const float*)d_in[9];
    const float* bo  = (const float*)d_in[10];
    const float* gnw = (const float*)d_in[11];
    const float* gnb = (const float*)d_in[12];
    float* out = (float*)d_out;

    // workspace layout
    char* w = (char*)d_ws;
    __bf16* xb      = (__bf16*)w;               w += MAT * 2;            // 8.4MB
    __bf16* wqkvg_t = (__bf16*)w;               w += MAT * 2;            // 8.4MB
    __bf16* wo_t    = (__bf16*)w;               w += (size_t)DMODEL * DMODEL * 2;
    float*  bqkvg   = (float*)w;                w += 4096 * 4;
    __bf16* qb      = (__bf16*)w;               w += MAT * 2;
    __bf16* kb      = (__bf16*)w;               w += MAT * 2;
    __bf16* vb      = (__bf16*)w;               w += MAT * 2;
    __bf16* gb      = (__bf16*)w;               w += MAT * 2;
    float*  ret     = (float*)w;                w += MAT * 4;            // 16.8MB
    __bf16* yb      = (__bf16*)w;               w += MAT * 2;
    float*  part    = (float*)w;                w += 512 * 2 * 4;
    float*  stats   = (float*)w;                w += 64 * 4;
    // vt aliases xb: xb is dead after the QKVG GEMM, transpose_v runs after it.
    __bf16* vt      = xb;

    // zero ret early (overlaps with prep); retention atomically accumulates
    hipMemsetAsync(ret, 0, MAT * 4, stream);

    // 1) prep
    cvt_x_kernel<<<2048, 256, 0, stream>>>(x, xb);
    {
        dim3 grid(32, 32, 5);
        transpose_w_kernel<<<grid, 256, 0, stream>>>(Wq, Wk, Wv, Wg, Wo,
                                                     wqkvg_t, wo_t);
    }
    pack_bias_kernel<<<16, 256, 0, stream>>>(bq, bk, bv, bg, bqkvg);

    // 2) fused QKVG projection GEMM (4096 x 4096 x 1024)
    {
        dim3 grid(32, 32);
        gemm_mfma_kernel<0><<<grid, 256, 0, stream>>>(
            xb, wqkvg_t, bqkvg, qb, kb, vb, gb, nullptr,
            M_TOT, 4096, DMODEL);
    }

    // 3) rotary xpos + V transpose (vt overwrites xb — safe, GEMM is done)
    rotary_bf16_kernel<<<B * S, 256, 0, stream>>>(qb, kb);
    {
        dim3 grid(32, 16, 2);
        transpose_v_kernel<<<grid, 256, 0, stream>>>(vb, vt);
    }

    // 4) retention (MFMA, split-j balanced, atomic accumulate)
    {
        dim3 grid(48, 16, 2);
        retention_mfma_kernel<<<grid, 256, 0, stream>>>(qb, kb, vt, ret);
    }

    // 5) group norm + silu gate
    {
        dim3 grid(16, 32);
        gn_stats1_kernel<<<grid, 256, 0, stream>>>(ret, part);
    }
    gn_stats2_kernel<<<1, 64, 0, stream>>>(part, stats);
    gn_apply_kernel<<<2048, 256, 0, stream>>>(ret, gb, yb, stats, gnw, gnb);

    // 6) output GEMM (4096 x 1024 x 1024), f32 out
    {
        dim3 grid(8, 32);
        gemm_mfma_kernel<1><<<grid, 256, 0, stream>>>(
            yb, wo_t, bo, nullptr, nullptr, nullptr, nullptr, out,
            M_TOT, DMODEL, DMODEL);
    }
}

// Round 4
// 169.586 us; speedup vs baseline: 1.2295x; 1.2295x over previous
//
#include <hip/hip_runtime.h>
#include <math.h>

constexpr int B = 2;
constexpr int S = 2048;
constexpr int DMODEL = 1024;
constexpr int H = 16;
constexpr int M_TOT = B * S;                     // 4096
constexpr size_t MAT = (size_t)B * S * DMODEL;   // 4,194,304 elements

typedef __attribute__((ext_vector_type(8))) __bf16 bf16x8;
typedef __attribute__((ext_vector_type(4))) float f32x4;

#define GLOAD16(g, l) __builtin_amdgcn_global_load_lds( \
    (const __attribute__((address_space(1))) void*)(g), \
    (__attribute__((address_space(3))) void*)(l), 16, 0, 0)

__device__ __forceinline__ float bf2f(__bf16 v) { return (float)v; }
__device__ __forceinline__ __bf16 f2bf(float v) { return (__bf16)v; }
__device__ __forceinline__ float silu(float z) { return z / (1.0f + expf(-z)); }

// ---------------------------------------------------------------------------
// Prep: x fp32 -> bf16 (8 elems / thread)
// ---------------------------------------------------------------------------
__global__ __launch_bounds__(256) void cvt_x_kernel(const float* __restrict__ x,
                                                    __bf16* __restrict__ xb)
{
    const size_t p = (size_t)blockIdx.x * 256 + threadIdx.x;  // group of 8
    const float4 a = reinterpret_cast<const float4*>(x)[2 * p];
    const float4 b = reinterpret_cast<const float4*>(x)[2 * p + 1];
    bf16x8 o;
    o[0] = f2bf(a.x); o[1] = f2bf(a.y); o[2] = f2bf(a.z); o[3] = f2bf(a.w);
    o[4] = f2bf(b.x); o[5] = f2bf(b.y); o[6] = f2bf(b.z); o[7] = f2bf(b.w);
    reinterpret_cast<bf16x8*>(xb)[p] = o;
}

// ---------------------------------------------------------------------------
// Prep: transpose + convert weights. z = 0..3 -> Wq,Wk,Wv,Wg into wqkvg_t
// (row n_global = z*1024 + n, col k). z = 4 -> Wo into wo_t.
// ---------------------------------------------------------------------------
__global__ __launch_bounds__(256) void transpose_w_kernel(
    const float* Wq, const float* Wk, const float* Wv, const float* Wg,
    const float* Wo, __bf16* __restrict__ wqkvg_t, __bf16* __restrict__ wo_t)
{
    __shared__ float tile[32][33];
    const int z = blockIdx.z;
    const float* W = (z == 0) ? Wq : (z == 1) ? Wk : (z == 2) ? Wv
                    : (z == 3) ? Wg : Wo;
    const int n0 = blockIdx.x * 32, k0 = blockIdx.y * 32;
    const int tx = threadIdx.x & 31, ty = threadIdx.x >> 5;  // 32 x 8

    #pragma unroll
    for (int i = 0; i < 32; i += 8)
        tile[ty + i][tx] = W[(size_t)(k0 + ty + i) * DMODEL + n0 + tx];
    __syncthreads();
    #pragma unroll
    for (int i = 0; i < 32; i += 8) {
        const int n = n0 + ty + i, kk = k0 + tx;
        const __bf16 val = f2bf(tile[tx][ty + i]);
        if (z < 4) wqkvg_t[((size_t)z * 1024 + n) * DMODEL + kk] = val;
        else       wo_t[(size_t)n * DMODEL + kk] = val;
    }
}

__global__ __launch_bounds__(256) void pack_bias_kernel(
    const float* bq, const float* bk, const float* bv, const float* bg,
    float* __restrict__ bqkvg)
{
    const int i = blockIdx.x * 256 + threadIdx.x;  // 0..4095
    const float* src = ((i >> 10) == 0) ? bq : ((i >> 10) == 1) ? bk
                      : ((i >> 10) == 2) ? bv : bg;
    bqkvg[i] = src[i & 1023];
}

// ---------------------------------------------------------------------------
// MFMA GEMM: C = A(MxK,bf16) @ Bt(NxK,bf16)^T + bias.
// 128x128 tile, BK=32, 256 threads (4 waves 2x2 of 64x64), global_load_lds.
// OUTMODE 0: bf16 out split into 4 buffers of width 1024 by col/1024.
// OUTMODE 1: f32 out, width N.
// ---------------------------------------------------------------------------
template <int OUTMODE>
__global__ __launch_bounds__(256) void gemm_mfma_kernel(
    const __bf16* __restrict__ A, const __bf16* __restrict__ Bt,
    const float* __restrict__ bias,
    __bf16* o0, __bf16* o1, __bf16* o2, __bf16* o3,
    float* fout, int M, int N, int K)
{
    __shared__ __bf16 a_lds[128 * 32];
    __shared__ __bf16 b_lds[128 * 32];

    const int t = threadIdx.x, wv = t >> 6, ln = t & 63;
    const int row0 = blockIdx.y * 128, col0 = blockIdx.x * 128;
    const int wr = (wv >> 1) * 64, wc = (wv & 1) * 64;
    const int lrow = ln & 15, lk8 = (ln >> 4) * 8;

    f32x4 acc[4][4] = {};

    for (int k0 = 0; k0 < K; k0 += 32) {
        __syncthreads();
        #pragma unroll
        for (int p = 0; p < 2; ++p) {
            const int ci = p * 256 + t;
            GLOAD16(A + (size_t)(row0 + (ci >> 2)) * K + k0 + (ci & 3) * 8,
                    (char*)a_lds + p * 4096 + wv * 1024);
            GLOAD16(Bt + (size_t)(col0 + (ci >> 2)) * K + k0 + (ci & 3) * 8,
                    (char*)b_lds + p * 4096 + wv * 1024);
        }
        __syncthreads();

        bf16x8 af[4], bf[4];
        #pragma unroll
        for (int mi = 0; mi < 4; ++mi)
            af[mi] = *reinterpret_cast<const bf16x8*>(
                &a_lds[(wr + mi * 16 + lrow) * 32 + lk8]);
        #pragma unroll
        for (int ni = 0; ni < 4; ++ni)
            bf[ni] = *reinterpret_cast<const bf16x8*>(
                &b_lds[(wc + ni * 16 + lrow) * 32 + lk8]);
        #pragma unroll
        for (int mi = 0; mi < 4; ++mi)
            #pragma unroll
            for (int ni = 0; ni < 4; ++ni)
                acc[mi][ni] = __builtin_amdgcn_mfma_f32_16x16x32_bf16(
                    af[mi], bf[ni], acc[mi][ni], 0, 0, 0);
    }

    if (OUTMODE == 0) {
        const int sel = col0 >> 10;
        __bf16* outp = (sel == 0) ? o0 : (sel == 1) ? o1 : (sel == 2) ? o2 : o3;
        #pragma unroll
        for (int mi = 0; mi < 4; ++mi) {
            #pragma unroll
            for (int ni = 0; ni < 4; ++ni) {
                const int cfull = col0 + wc + ni * 16 + (ln & 15);
                const float bs = bias[cfull];
                #pragma unroll
                for (int reg = 0; reg < 4; ++reg) {
                    const int r = row0 + wr + mi * 16 + (ln >> 4) * 4 + reg;
                    outp[(size_t)r * 1024 + (cfull & 1023)] =
                        f2bf(acc[mi][ni][reg] + bs);
                }
            }
        }
    } else {
        #pragma unroll
        for (int mi = 0; mi < 4; ++mi) {
            #pragma unroll
            for (int ni = 0; ni < 4; ++ni) {
                const int c = col0 + wc + ni * 16 + (ln & 15);
                const float bs = bias[c];
                #pragma unroll
                for (int reg = 0; reg < 4; ++reg) {
                    const int r = row0 + wr + mi * 16 + (ln >> 4) * 4 + reg;
                    fout[(size_t)r * N + c] = acc[mi][ni][reg] + bs;
                }
            }
        }
    }
}

// ---------------------------------------------------------------------------
// xPos rotary on bf16 q (scale) and k (1/scale), in place.
// ---------------------------------------------------------------------------
__global__ __launch_bounds__(256) void rotary_bf16_kernel(__bf16* __restrict__ q,
                                                          __bf16* __restrict__ k)
{
    const int bs = blockIdx.x;
    const int s  = bs & (S - 1);
    const int h  = threadIdx.x >> 4;
    const int j  = threadIdx.x & 15;

    const float inv_freq = powf(10000.0f, -(float)j / 16.0f);
    const float freq = (float)s * inv_freq;
    const float c  = cosf(freq);
    const float sn = sinf(freq);
    const float base = (2.0f * j + 0.4f * 32.0f) / (1.4f * 32.0f);
    const float p    = ((float)s - (float)(S / 2)) / 512.0f;
    const float sc   = powf(base, p);

    const size_t off = (size_t)bs * DMODEL + h * 64 + 2 * j;

    const float q0 = bf2f(q[off]), q1 = bf2f(q[off + 1]);
    q[off]     = f2bf((q0 * c - q1 * sn) * sc);
    q[off + 1] = f2bf((q1 * c + q0 * sn) * sc);

    const float isc = 1.0f / sc;
    const float k0 = bf2f(k[off]), k1 = bf2f(k[off + 1]);
    k[off]     = f2bf((k0 * c - k1 * sn) * isc);
    k[off + 1] = f2bf((k1 * c + k0 * sn) * isc);
}

// ---------------------------------------------------------------------------
// Transpose V per (b,h): vb[b*S+s][h*64+d] -> vt[(b*16+h)*64+d][s]
// ---------------------------------------------------------------------------
__global__ __launch_bounds__(256) void transpose_v_kernel(
    const __bf16* __restrict__ vb, __bf16* __restrict__ vt)
{
    __shared__ __bf16 tile[64][72];
    const int stile = blockIdx.x;   // 0..31
    const int h = blockIdx.y, b = blockIdx.z;
    const int t = threadIdx.x;
    #pragma unroll
    for (int p = 0; p < 2; ++p) {
        const int ci = p * 256 + t;
        const int r = ci >> 3, c8 = (ci & 7) * 8;   // r = s_loc, c8 = d base
        *reinterpret_cast<bf16x8*>(&tile[r][c8]) =
            *reinterpret_cast<const bf16x8*>(
                &vb[(size_t)(b * S + stile * 64 + r) * DMODEL + h * 64 + c8]);
    }
    __syncthreads();
    #pragma unroll
    for (int p = 0; p < 2; ++p) {
        const int ci = p * 256 + t;
        const int d = ci >> 3, s8 = (ci & 7) * 8;
        bf16x8 o;
        #pragma unroll
        for (int w = 0; w < 8; ++w) o[w] = tile[s8 + w][d];
        *reinterpret_cast<bf16x8*>(
            &vt[((size_t)(b * 16 + h) * 64 + d) * 2048 + stile * 64 + s8]) = o;
    }
}

// ---------------------------------------------------------------------------
// Retention via MFMA. q-tile = 128 rows, 4 waves x 32 rows. K/V tiles of 64.
// Job jb per (b,h): jb<16 -> st=jb, j-tiles [0, min(2st+1,15)] -> ret;
//                   jb>=16 -> st=jb-8 (8..15), j-tiles [16, 2st+1] -> ret2.
// No atomics: ret2 holds the second partial for rows s>=1024; GN fuses add.
// S^T = mfma(K,Q) so P writes are packed b64 transpose-on-write.
// All LDS tiles 128B rows with XOR swizzle (byte ^= (row&7)<<4).
// T14: next tile's K/V global loads issued into regs before the MFMA cluster.
// ---------------------------------------------------------------------------
__global__ __launch_bounds__(256) void retention_mfma_kernel(
    const __bf16* __restrict__ qg, const __bf16* __restrict__ kg,
    const __bf16* __restrict__ vtg, float* __restrict__ ret,
    float* __restrict__ ret2)
{
    __shared__ __bf16 q_lds[128 * 64];
    __shared__ __bf16 k_lds[64 * 64];
    __shared__ __bf16 vt_lds[64 * 64];
    __shared__ __bf16 p_lds[128 * 64];

    const int jb = blockIdx.x, h = blockIdx.y, b = blockIdx.z;
    int st, jlo, jhi;
    if (jb < 16) { st = jb; jlo = 0; jhi = (2 * st + 1 < 15) ? 2 * st + 1 : 15; }
    else         { st = jb - 8; jlo = 16; jhi = 2 * st + 1; }
    const int s0 = st * 128;
    const int t = threadIdx.x, wv = t >> 6, ln = t & 63;
    const int lrow = ln & 15, lk8 = (ln >> 4) * 8;

    const float gamma  = 1.0f - exp2f(-5.0f - (float)h);
    const float l2g    = log2f(gamma);
    const float ginv   = exp2f(-l2g);           // 1/gamma
    const float ginv16 = exp2f(-16.0f * l2g);   // gamma^-16
    const size_t base  = (size_t)b * S * DMODEL + h * 64;       // q,k row-major
    const size_t baset = (size_t)(b * 16 + h) * 64 * 2048;      // vt [d][s]

    // stage q tile 128x64 (swizzled)
    #pragma unroll
    for (int p = 0; p < 4; ++p) {
        const int ci = p * 256 + t;
        const int r = ci >> 3, c8 = (ci & 7) * 8;
        *(bf16x8*)((char*)q_lds + r * 128 + ((c8 * 2) ^ ((r & 7) << 4))) =
            *reinterpret_cast<const bf16x8*>(
                &qg[base + (size_t)(s0 + r) * DMODEL + c8]);
    }

    // staging geometry for 64x64 k/v tiles: 2 chunks of 32 rows
    const int sr = t >> 3, sc8 = (t & 7) * 8;
    const int soff0 = sr * 128 + ((sc8 * 2) ^ ((sr & 7) << 4));
    const int soff1 = (sr + 32) * 128 + ((sc8 * 2) ^ ((sr & 7) << 4));

    bf16x8 kr0, kr1, vr0, vr1;
    {
        const int j0 = jlo * 64;
        kr0 = *reinterpret_cast<const bf16x8*>(
            &kg[base + (size_t)(j0 + sr) * DMODEL + sc8]);
        kr1 = *reinterpret_cast<const bf16x8*>(
            &kg[base + (size_t)(j0 + 32 + sr) * DMODEL + sc8]);
        vr0 = *reinterpret_cast<const bf16x8*>(
            &vtg[baset + (size_t)sr * 2048 + j0 + sc8]);
        vr1 = *reinterpret_cast<const bf16x8*>(
            &vtg[baset + (size_t)(sr + 32) * 2048 + j0 + sc8]);
    }

    f32x4 oacc[2][4] = {};

    for (int jt = jlo; jt <= jhi; ++jt) {
        const int j0 = jt * 64;
        __syncthreads();                    // prev iter's LDS reads done
        *(bf16x8*)((char*)k_lds  + soff0) = kr0;
        *(bf16x8*)((char*)k_lds  + soff1) = kr1;
        *(bf16x8*)((char*)vt_lds + soff0) = vr0;
        *(bf16x8*)((char*)vt_lds + soff1) = vr1;
        __syncthreads();

        // T14: issue next tile's global loads now; they complete under MFMA
        if (jt < jhi) {
            const int j0n = (jt + 1) * 64;
            kr0 = *reinterpret_cast<const bf16x8*>(
                &kg[base + (size_t)(j0n + sr) * DMODEL + sc8]);
            kr1 = *reinterpret_cast<const bf16x8*>(
                &kg[base + (size_t)(j0n + 32 + sr) * DMODEL + sc8]);
            vr0 = *reinterpret_cast<const bf16x8*>(
                &vtg[baset + (size_t)sr * 2048 + j0n + sc8]);
            vr1 = *reinterpret_cast<const bf16x8*>(
                &vtg[baset + (size_t)(sr + 32) * 2048 + j0n + sc8]);
        }

        // QK^T (swapped): sacc[ni][mi], lane holds j=mi*16+(ln>>4)*4+reg,
        // i = wv*32 + ni*16 + (ln&15)
        f32x4 sacc[2][4] = {};
        #pragma unroll
        for (int ks = 0; ks < 2; ++ks) {
            bf16x8 qf[2];
            #pragma unroll
            for (int ni = 0; ni < 2; ++ni) {
                const int qrow = wv * 32 + ni * 16 + lrow;
                qf[ni] = *(const bf16x8*)((char*)q_lds + qrow * 128 +
                    (((ks * 32 + lk8) * 2) ^ ((qrow & 7) << 4)));
            }
            #pragma unroll
            for (int mi = 0; mi < 4; ++mi) {
                const int krow = mi * 16 + lrow;
                const bf16x8 kf = *(const bf16x8*)((char*)k_lds + krow * 128 +
                    (((ks * 32 + lk8) * 2) ^ ((krow & 7) << 4)));
                #pragma unroll
                for (int ni = 0; ni < 2; ++ni)
                    sacc[ni][mi] = __builtin_amdgcn_mfma_f32_16x16x32_bf16(
                        kf, qf[ni], sacc[ni][mi], 0, 0, 0);
            }
        }

        // decay + causal mask, pack P[i][j] as b64
        const int d0 = s0 + wv * 32 + (ln & 15) - (ln >> 4) * 4 - j0;
        const bool diag = (jt >= 2 * st);
        #pragma unroll
        for (int ni = 0; ni < 2; ++ni) {
            float wmi = exp2f((float)(d0 + 16 * ni) * l2g);
            #pragma unroll
            for (int mi = 0; mi < 4; ++mi) {
                float wr = wmi;
                ushort4 pk;
                unsigned short* pkp = (unsigned short*)&pk;
                #pragma unroll
                for (int reg = 0; reg < 4; ++reg) {
                    float wgt = wr;
                    if (diag && (d0 + 16 * ni - 16 * mi - reg) < 0) wgt = 0.0f;
                    const __bf16 pb = f2bf(sacc[ni][mi][reg] * wgt);
                    pkp[reg] = *(const unsigned short*)&pb;
                    wr *= ginv;
                }
                const int prow = wv * 32 + ni * 16 + (ln & 15);
                const int jb8 = mi * 16 + (ln >> 4) * 4;
                *(ushort4*)((char*)p_lds + prow * 128 +
                            ((jb8 * 2) ^ ((prow & 7) << 4))) = pk;
                wmi *= ginv16;
            }
        }

        // PV: oacc[ni][nd] += P(32x64) @ V(64x64); P rows wave-private
        #pragma unroll
        for (int ks = 0; ks < 2; ++ks) {
            bf16x8 vf[4];
            #pragma unroll
            for (int nd = 0; nd < 4; ++nd) {
                const int vrow = nd * 16 + lrow;
                vf[nd] = *(const bf16x8*)((char*)vt_lds + vrow * 128 +
                    (((ks * 32 + lk8) * 2) ^ ((vrow & 7) << 4)));
            }
            #pragma unroll
            for (int ni = 0; ni < 2; ++ni) {
                const int prow = wv * 32 + ni * 16 + lrow;
                const bf16x8 pf = *(const bf16x8*)((char*)p_lds + prow * 128 +
                    (((ks * 32 + lk8) * 2) ^ ((prow & 7) << 4)));
                #pragma unroll
                for (int nd = 0; nd < 4; ++nd)
                    oacc[ni][nd] = __builtin_amdgcn_mfma_f32_16x16x32_bf16(
                        pf, vf[nd], oacc[ni][nd], 0, 0, 0);
            }
        }
    }

    // scale by closed-form normalizer and store (no atomics)
    const float sc5h = exp2f(5.0f + (float)h);
    #pragma unroll
    for (int ni = 0; ni < 2; ++ni) {
        #pragma unroll
        for (int reg = 0; reg < 4; ++reg) {
            const int i = s0 + wv * 32 + ni * 16 + (ln >> 4) * 4 + reg;
            const float omg = 1.0f - exp2f((float)(i + 1) * l2g);
            const float invn = rsqrtf(omg * sc5h);
            if (jb < 16) {
                #pragma unroll
                for (int nd = 0; nd < 4; ++nd)
                    ret[base + (size_t)i * DMODEL + nd * 16 + (ln & 15)] =
                        oacc[ni][nd][reg] * invn;
            } else {
                const size_t o2 = ((size_t)b * 1024 + (i - 1024)) * 1024 + h * 64;
                #pragma unroll
                for (int nd = 0; nd < 4; ++nd)
                    ret2[o2 + nd * 16 + (ln & 15)] = oacc[ni][nd][reg] * invn;
            }
        }
    }
}

// ---------------------------------------------------------------------------
// GroupNorm stats, 2 stages. Stage 1 fuses the ret+ret2 partial add.
// ---------------------------------------------------------------------------
__global__ __launch_bounds__(256) void gn_stats1_kernel(
    const float* __restrict__ ret, const float* __restrict__ ret2,
    float* __restrict__ part)
{
    const int sl = blockIdx.x;          // 0..15 slice of 128 rows
    const int bh = blockIdx.y;          // 0..31
    const int b = bh >> 4, h = bh & 15;
    const size_t rowbase = ((size_t)b * S + sl * 128) * DMODEL + h * 64;
    const size_t rowbase2 = ((size_t)b * 1024 + sl * 128 - 1024) * DMODEL + h * 64;
    float sum = 0.0f, sq = 0.0f;
    #pragma unroll
    for (int it = 0; it < 8; ++it) {
        const int idx = it * 256 + threadIdx.x;  // float4 index
        const int row = idx >> 4;
        const int c4 = (idx & 15) * 4;
        float4 v = *reinterpret_cast<const float4*>(
            &ret[rowbase + (size_t)row * DMODEL + c4]);
        if (sl >= 8) {
            const float4 v2 = *reinterpret_cast<const float4*>(
                &ret2[rowbase2 + (size_t)row * DMODEL + c4]);
            v.x += v2.x; v.y += v2.y; v.z += v2.z; v.w += v2.w;
        }
        sum += v.x + v.y + v.z + v.w;
        sq  += v.x * v.x + v.y * v.y + v.z * v.z + v.w * v.w;
    }
    #pragma unroll
    for (int o = 32; o > 0; o >>= 1) {
        sum += __shfl_down(sum, o, 64);
        sq  += __shfl_down(sq, o, 64);
    }
    __shared__ float rs[4], rq[4];
    const int wid = threadIdx.x >> 6, lane = threadIdx.x & 63;
    if (lane == 0) { rs[wid] = sum; rq[wid] = sq; }
    __syncthreads();
    if (threadIdx.x == 0) {
        part[(bh * 16 + sl) * 2 + 0] = rs[0] + rs[1] + rs[2] + rs[3];
        part[(bh * 16 + sl) * 2 + 1] = rq[0] + rq[1] + rq[2] + rq[3];
    }
}

__global__ __launch_bounds__(64) void gn_stats2_kernel(const float* __restrict__ part,
                                                       float* __restrict__ stats)
{
    const int bh = threadIdx.x;
    if (bh < 32) {
        float s = 0.0f, q2 = 0.0f;
        for (int i = 0; i < 16; ++i) {
            s  += part[(bh * 16 + i) * 2 + 0];
            q2 += part[(bh * 16 + i) * 2 + 1];
        }
        const float inv_n = 1.0f / (float)(S * 64);
        const float mean = s * inv_n;
        const float var  = q2 * inv_n - mean * mean;
        stats[bh * 2 + 0] = mean;
        stats[bh * 2 + 1] = rsqrtf(var + 1e-5f);
    }
}

// ---------------------------------------------------------------------------
// y = ((ret[+ret2] - mean) * rstd * gn_w[h] + gn_b[h]) * silu(g), bf16 out.
// ---------------------------------------------------------------------------
__global__ __launch_bounds__(256) void gn_apply_kernel(
    const float* __restrict__ ret, const float* __restrict__ ret2,
    const __bf16* __restrict__ g, __bf16* __restrict__ y,
    const float* __restrict__ stats,
    const float* __restrict__ gnw, const float* __restrict__ gnb)
{
    const size_t p = (size_t)blockIdx.x * 256 + threadIdx.x;  // group of 8
    const size_t el = p * 8;
    const int col = (int)(el & (DMODEL - 1));
    const int s   = (int)((el >> 10) & 2047);
    const int h   = col >> 6;
    const int b   = (int)(el >> 21);              // S*DMODEL = 2^21
    const int bh  = b * H + h;
    const float mean = stats[bh * 2 + 0];
    const float w    = stats[bh * 2 + 1] * gnw[h];
    const float bb   = gnb[h];

    float4 r0 = reinterpret_cast<const float4*>(ret)[2 * p];
    float4 r1 = reinterpret_cast<const float4*>(ret)[2 * p + 1];
    if (s >= 1024) {
        const size_t q2 = ((size_t)b * 1024 + (s - 1024)) * 1024 + col;
        const float4 a0 = *reinterpret_cast<const float4*>(&ret2[q2]);
        const float4 a1 = *reinterpret_cast<const float4*>(&ret2[q2 + 4]);
        r0.x += a0.x; r0.y += a0.y; r0.z += a0.z; r0.w += a0.w;
        r1.x += a1.x; r1.y += a1.y; r1.z += a1.z; r1.w += a1.w;
    }
    const bf16x8 gv = reinterpret_cast<const bf16x8*>(g)[p];
    bf16x8 o;
    o[0] = f2bf(((r0.x - mean) * w + bb) * silu(bf2f(gv[0])));
    o[1] = f2bf(((r0.y - mean) * w + bb) * silu(bf2f(gv[1])));
    o[2] = f2bf(((r0.z - mean) * w + bb) * silu(bf2f(gv[2])));
    o[3] = f2bf(((r0.w - mean) * w + bb) * silu(bf2f(gv[3])));
    o[4] = f2bf(((r1.x - mean) * w + bb) * silu(bf2f(gv[4])));
    o[5] = f2bf(((r1.y - mean) * w + bb) * silu(bf2f(gv[5])));
    o[6] = f2bf(((r1.z - mean) * w + bb) * silu(bf2f(gv[6])));
    o[7] = f2bf(((r1.w - mean) * w + bb) * silu(bf2f(gv[7])));
    reinterpret_cast<bf16x8*>(y)[p] = o;
}

// ---------------------------------------------------------------------------
extern "C" void kernel_launch(void* const* d_in, const int* in_sizes, int n_in,
                              void* d_out, int out_size, void* d_ws, size_t ws_size,
                              hipStream_t stream)
{
    const float* x   = (const float*)d_in[0];
    const float* Wq  = (const float*)d_in[1];
    const float* bq  = (const float*)d_in[2];
    const float* Wk  = (const float*)d_in[3];
    const float* bk  = (const float*)d_in[4];
    const float* Wv  = (const float*)d_in[5];
    const float* bv  = (const float*)d_in[6];
    const float* Wg  = (const float*)d_in[7];
    const float* bg  = (const float*)d_in[8];
    const float* Wo  = (const float*)d_in[9];
    const float* bo  = (const float*)d_in[10];
    const float* gnw = (const float*)d_in[11];
    const float* gnb = (const float*)d_in[12];
    float* out = (float*)d_out;

    // workspace layout
    char* w = (char*)d_ws;
    __bf16* xb      = (__bf16*)w;               w += MAT * 2;            // 8.4MB
    __bf16* wqkvg_t = (__bf16*)w;               w += MAT * 2;            // 8.4MB
    __bf16* wo_t    = (__bf16*)w;               w += (size_t)DMODEL * DMODEL * 2;
    float*  bqkvg   = (float*)w;                w += 4096 * 4;
    __bf16* qb      = (__bf16*)w;               w += MAT * 2;
    __bf16* kb      = (__bf16*)w;               w += MAT * 2;
    __bf16* vb      = (__bf16*)w;               w += MAT * 2;
    __bf16* gb      = (__bf16*)w;               w += MAT * 2;
    float*  ret     = (float*)w;                w += MAT * 4;            // 16.8MB
    __bf16* yb      = (__bf16*)w;               w += MAT * 2;
    float*  part    = (float*)w;                w += 512 * 2 * 4;
    float*  stats   = (float*)w;                w += 64 * 4;
    // aliases over dead prep buffers:
    __bf16* vt   = xb;                 // xb dead after QKVG GEMM
    float*  ret2 = (float*)wqkvg_t;    // wqkvg_t dead after QKVG GEMM (8.4MB fits)

    // 1) prep
    cvt_x_kernel<<<2048, 256, 0, stream>>>(x, xb);
    {
        dim3 grid(32, 32, 5);
        transpose_w_kernel<<<grid, 256, 0, stream>>>(Wq, Wk, Wv, Wg, Wo,
                                                     wqkvg_t, wo_t);
    }
    pack_bias_kernel<<<16, 256, 0, stream>>>(bq, bk, bv, bg, bqkvg);

    // 2) fused QKVG projection GEMM (4096 x 4096 x 1024)
    {
        dim3 grid(32, 32);
        gemm_mfma_kernel<0><<<grid, 256, 0, stream>>>(
            xb, wqkvg_t, bqkvg, qb, kb, vb, gb, nullptr,
            M_TOT, 4096, DMODEL);
    }

    // 3) rotary xpos + V transpose (vt overwrites xb — safe, GEMM is done)
    rotary_bf16_kernel<<<B * S, 256, 0, stream>>>(qb, kb);
    {
        dim3 grid(32, 16, 2);
        transpose_v_kernel<<<grid, 256, 0, stream>>>(vb, vt);
    }

    // 4) retention (MFMA, 128-row q tiles, split-j, no atomics)
    {
        dim3 grid(24, 16, 2);
        retention_mfma_kernel<<<grid, 256, 0, stream>>>(qb, kb, vt, ret, ret2);
    }

    // 5) group norm + silu gate (fuses ret+ret2)
    {
        dim3 grid(16, 32);
        gn_stats1_kernel<<<grid, 256, 0, stream>>>(ret, ret2, part);
    }
    gn_stats2_kernel<<<1, 64, 0, stream>>>(part, stats);
    gn_apply_kernel<<<2048, 256, 0, stream>>>(ret, ret2, gb, yb, stats, gnw, gnb);

    // 6) output GEMM (4096 x 1024 x 1024), f32 out
    {
        dim3 grid(8, 32);
        gemm_mfma_kernel<1><<<grid, 256, 0, stream>>>(
            yb, wo_t, bo, nullptr, nullptr, nullptr, nullptr, out,
            M_TOT, DMODEL, DMODEL);
    }
}

// Round 5
// 153.203 us; speedup vs baseline: 1.3609x; 1.1069x over previous
//
#include <hip/hip_runtime.h>
#include <math.h>

constexpr int B = 2;
constexpr int S = 2048;
constexpr int DMODEL = 1024;
constexpr int H = 16;
constexpr int M_TOT = B * S;                     // 4096
constexpr size_t MAT = (size_t)B * S * DMODEL;   // 4,194,304 elements

typedef __attribute__((ext_vector_type(8))) __bf16 bf16x8;
typedef __attribute__((ext_vector_type(4))) float f32x4;

#define GLOAD16(g, l) __builtin_amdgcn_global_load_lds( \
    (const __attribute__((address_space(1))) void*)(g), \
    (__attribute__((address_space(3))) void*)(l), 16, 0, 0)

__device__ __forceinline__ float bf2f(__bf16 v) { return (float)v; }
__device__ __forceinline__ __bf16 f2bf(float v) { return (__bf16)v; }
__device__ __forceinline__ float silu(float z) { return z / (1.0f + expf(-z)); }

// ---------------------------------------------------------------------------
// Prep: x fp32 -> bf16 (8 elems / thread)
// ---------------------------------------------------------------------------
__global__ __launch_bounds__(256) void cvt_x_kernel(const float* __restrict__ x,
                                                    __bf16* __restrict__ xb)
{
    const size_t p = (size_t)blockIdx.x * 256 + threadIdx.x;  // group of 8
    const float4 a = reinterpret_cast<const float4*>(x)[2 * p];
    const float4 b = reinterpret_cast<const float4*>(x)[2 * p + 1];
    bf16x8 o;
    o[0] = f2bf(a.x); o[1] = f2bf(a.y); o[2] = f2bf(a.z); o[3] = f2bf(a.w);
    o[4] = f2bf(b.x); o[5] = f2bf(b.y); o[6] = f2bf(b.z); o[7] = f2bf(b.w);
    reinterpret_cast<bf16x8*>(xb)[p] = o;
}

// ---------------------------------------------------------------------------
// Prep: transpose + convert weights. z = 0..3 -> Wq,Wk,Wv,Wg into wqkvg_t
// (row n_global = z*1024 + n, col k). z = 4 -> Wo into wo_t.
// ---------------------------------------------------------------------------
__global__ __launch_bounds__(256) void transpose_w_kernel(
    const float* Wq, const float* Wk, const float* Wv, const float* Wg,
    const float* Wo, __bf16* __restrict__ wqkvg_t, __bf16* __restrict__ wo_t)
{
    __shared__ float tile[32][33];
    const int z = blockIdx.z;
    const float* W = (z == 0) ? Wq : (z == 1) ? Wk : (z == 2) ? Wv
                    : (z == 3) ? Wg : Wo;
    const int n0 = blockIdx.x * 32, k0 = blockIdx.y * 32;
    const int tx = threadIdx.x & 31, ty = threadIdx.x >> 5;  // 32 x 8

    #pragma unroll
    for (int i = 0; i < 32; i += 8)
        tile[ty + i][tx] = W[(size_t)(k0 + ty + i) * DMODEL + n0 + tx];
    __syncthreads();
    #pragma unroll
    for (int i = 0; i < 32; i += 8) {
        const int n = n0 + ty + i, kk = k0 + tx;
        const __bf16 val = f2bf(tile[tx][ty + i]);
        if (z < 4) wqkvg_t[((size_t)z * 1024 + n) * DMODEL + kk] = val;
        else       wo_t[(size_t)n * DMODEL + kk] = val;
    }
}

__global__ __launch_bounds__(256) void pack_bias_kernel(
    const float* bq, const float* bk, const float* bv, const float* bg,
    float* __restrict__ bqkvg)
{
    const int i = blockIdx.x * 256 + threadIdx.x;  // 0..4095
    const float* src = ((i >> 10) == 0) ? bq : ((i >> 10) == 1) ? bk
                      : ((i >> 10) == 2) ? bv : bg;
    bqkvg[i] = src[i & 1023];
}

// ---------------------------------------------------------------------------
// 8-wave 256x256 phase-interleaved QKVG GEMM (K=1024 fixed).
// Ring of 4 LDS buffers (BK=32 K-tiles), counted vmcnt(8), setprio around
// MFMA clusters, XOR-swizzled LDS via pre-swizzled global source.
// C = A(4096x1024) @ Bt(4096x1024)^T + bias; bf16 out, split by col/1024.
// ---------------------------------------------------------------------------
__device__ __forceinline__ bf16x8 ldsfrag(const char* base, int row, int kbyte)
{
    return *(const bf16x8*)(base + row * 64 + (kbyte ^ ((row & 3) << 4)));
}

__device__ __forceinline__ void stage_panel(const __bf16* __restrict__ src,
                                            int srow0, int k0, char* bufbase,
                                            int tid, int wv)
{
    #pragma unroll
    for (int j = 0; j < 2; ++j) {
        const int r  = j * 128 + (tid >> 2);
        const int cb = ((tid & 3) * 16) ^ ((r & 3) << 4);
        GLOAD16((const char*)(src + ((size_t)(srow0 + r) << 10) + k0) + cb,
                bufbase + j * 8192 + wv * 1024);
    }
}

__global__ __launch_bounds__(512) void gemm_qkvg_8ph(
    const __bf16* __restrict__ A, const __bf16* __restrict__ Bt,
    const float* __restrict__ bias,
    __bf16* o0, __bf16* o1, __bf16* o2, __bf16* o3)
{
    extern __shared__ char lds[];   // 131072 B: A ring 4x16KB, B ring 4x16KB
    constexpr int NTK = 32;         // 1024 / 32

    const int tid = threadIdx.x, wv = tid >> 6, ln = tid & 63;
    const int wm = wv >> 2, wn = wv & 3;

    // XCD-aware swizzle (nwg=256, 8 XCDs, cpx=32) then 16x16 block grid
    int bid = blockIdx.x;
    bid = (bid & 7) * 32 + (bid >> 3);
    const int bx = bid & 15, by = bid >> 4;
    const int row0 = by * 256, col0 = bx * 256;

    const int lrow = ln & 15;
    const int kb   = (ln >> 4) * 16;   // k byte offset within 64B row

    f32x4 acc[8][4] = {};

    // prologue: stage K-tiles 0,1,2
    #pragma unroll
    for (int tt = 0; tt < 3; ++tt) {
        stage_panel(A,  row0, tt * 32, lds + (tt & 3) * 16384, tid, wv);
        stage_panel(Bt, col0, tt * 32, lds + 65536 + (tt & 3) * 16384, tid, wv);
    }
    asm volatile("s_waitcnt vmcnt(8)" ::: "memory");
    __builtin_amdgcn_s_barrier();
    __builtin_amdgcn_sched_barrier(0);

    for (int t = 0; t < NTK; ++t) {
        const char* ab = lds + (t & 3) * 16384;
        const char* bb = lds + 65536 + (t & 3) * 16384;
        bf16x8 af[4], bf[4];

        // ---- phase 0: m-frags 0-3 ----
        #pragma unroll
        for (int mf = 0; mf < 4; ++mf)
            af[mf] = ldsfrag(ab, wm * 128 + mf * 16 + lrow, kb);
        #pragma unroll
        for (int nf = 0; nf < 4; ++nf)
            bf[nf] = ldsfrag(bb, wn * 64 + nf * 16 + lrow, kb);
        if (t + 3 < NTK)
            stage_panel(A, row0, (t + 3) * 32,
                        lds + ((t + 3) & 3) * 16384, tid, wv);
        asm volatile("" ::: "memory");
        __builtin_amdgcn_s_barrier();
        __builtin_amdgcn_sched_barrier(0);
        __builtin_amdgcn_s_setprio(1);
        #pragma unroll
        for (int mf = 0; mf < 4; ++mf)
            #pragma unroll
            for (int nf = 0; nf < 4; ++nf)
                acc[mf][nf] = __builtin_amdgcn_mfma_f32_16x16x32_bf16(
                    af[mf], bf[nf], acc[mf][nf], 0, 0, 0);
        __builtin_amdgcn_s_setprio(0);
        asm volatile("" ::: "memory");
        __builtin_amdgcn_s_barrier();
        __builtin_amdgcn_sched_barrier(0);

        // ---- phase 1: m-frags 4-7 (bf reused) ----
        #pragma unroll
        for (int mf = 0; mf < 4; ++mf)
            af[mf] = ldsfrag(ab, wm * 128 + 64 + mf * 16 + lrow, kb);
        if (t + 3 < NTK)
            stage_panel(Bt, col0, (t + 3) * 32,
                        lds + 65536 + ((t + 3) & 3) * 16384, tid, wv);
        asm volatile("" ::: "memory");
        __builtin_amdgcn_s_barrier();
        __builtin_amdgcn_sched_barrier(0);
        __builtin_amdgcn_s_setprio(1);
        #pragma unroll
        for (int mf = 0; mf < 4; ++mf)
            #pragma unroll
            for (int nf = 0; nf < 4; ++nf)
                acc[4 + mf][nf] = __builtin_amdgcn_mfma_f32_16x16x32_bf16(
                    af[mf], bf[nf], acc[4 + mf][nf], 0, 0, 0);
        __builtin_amdgcn_s_setprio(0);

        // end-of-tile: counted wait publishing K-tile t+1 (never 0 until tail)
        if (t <= NTK - 4)
            asm volatile("s_waitcnt vmcnt(8)" ::: "memory");
        else if (t == NTK - 3)
            asm volatile("s_waitcnt vmcnt(4)" ::: "memory");
        else if (t == NTK - 2)
            asm volatile("s_waitcnt vmcnt(0)" ::: "memory");
        __builtin_amdgcn_s_barrier();
        __builtin_amdgcn_sched_barrier(0);
    }

    // epilogue: bias add + bf16 store; block maps to exactly one output
    const int sel = col0 >> 10;
    __bf16* outp = (sel == 0) ? o0 : (sel == 1) ? o1 : (sel == 2) ? o2 : o3;
    const int cb0 = col0 & 1023;
    #pragma unroll
    for (int mf = 0; mf < 8; ++mf) {
        #pragma unroll
        for (int nf = 0; nf < 4; ++nf) {
            const int cl = cb0 + wn * 64 + nf * 16 + (ln & 15);
            const float bs = bias[col0 + wn * 64 + nf * 16 + (ln & 15)];
            #pragma unroll
            for (int reg = 0; reg < 4; ++reg) {
                const int r = row0 + wm * 128 + mf * 16 + (ln >> 4) * 4 + reg;
                outp[(size_t)r * 1024 + cl] = f2bf(acc[mf][nf][reg] + bs);
            }
        }
    }
}

// ---------------------------------------------------------------------------
// MFMA GEMM (m97-style 128x128), kept for the Wo projection (N=1024).
// ---------------------------------------------------------------------------
__global__ __launch_bounds__(256) void gemm_mfma_kernel(
    const __bf16* __restrict__ A, const __bf16* __restrict__ Bt,
    const float* __restrict__ bias, float* fout, int M, int N, int K)
{
    __shared__ __bf16 a_lds[128 * 32];
    __shared__ __bf16 b_lds[128 * 32];

    const int t = threadIdx.x, wv = t >> 6, ln = t & 63;
    const int row0 = blockIdx.y * 128, col0 = blockIdx.x * 128;
    const int wr = (wv >> 1) * 64, wc = (wv & 1) * 64;
    const int lrow = ln & 15, lk8 = (ln >> 4) * 8;

    f32x4 acc[4][4] = {};

    for (int k0 = 0; k0 < K; k0 += 32) {
        __syncthreads();
        #pragma unroll
        for (int p = 0; p < 2; ++p) {
            const int ci = p * 256 + t;
            GLOAD16(A + (size_t)(row0 + (ci >> 2)) * K + k0 + (ci & 3) * 8,
                    (char*)a_lds + p * 4096 + wv * 1024);
            GLOAD16(Bt + (size_t)(col0 + (ci >> 2)) * K + k0 + (ci & 3) * 8,
                    (char*)b_lds + p * 4096 + wv * 1024);
        }
        __syncthreads();

        bf16x8 af[4], bf[4];
        #pragma unroll
        for (int mi = 0; mi < 4; ++mi)
            af[mi] = *reinterpret_cast<const bf16x8*>(
                &a_lds[(wr + mi * 16 + lrow) * 32 + lk8]);
        #pragma unroll
        for (int ni = 0; ni < 4; ++ni)
            bf[ni] = *reinterpret_cast<const bf16x8*>(
                &b_lds[(wc + ni * 16 + lrow) * 32 + lk8]);
        #pragma unroll
        for (int mi = 0; mi < 4; ++mi)
            #pragma unroll
            for (int ni = 0; ni < 4; ++ni)
                acc[mi][ni] = __builtin_amdgcn_mfma_f32_16x16x32_bf16(
                    af[mi], bf[ni], acc[mi][ni], 0, 0, 0);
    }

    #pragma unroll
    for (int mi = 0; mi < 4; ++mi) {
        #pragma unroll
        for (int ni = 0; ni < 4; ++ni) {
            const int c = col0 + wc + ni * 16 + (ln & 15);
            const float bs = bias[c];
            #pragma unroll
            for (int reg = 0; reg < 4; ++reg) {
                const int r = row0 + wr + mi * 16 + (ln >> 4) * 4 + reg;
                fout[(size_t)r * N + c] = acc[mi][ni][reg] + bs;
            }
        }
    }
}

// ---------------------------------------------------------------------------
// xPos rotary on bf16 q (scale) and k (1/scale), in place.
// ---------------------------------------------------------------------------
__global__ __launch_bounds__(256) void rotary_bf16_kernel(__bf16* __restrict__ q,
                                                          __bf16* __restrict__ k)
{
    const int bs = blockIdx.x;
    const int s  = bs & (S - 1);
    const int h  = threadIdx.x >> 4;
    const int j  = threadIdx.x & 15;

    const float inv_freq = powf(10000.0f, -(float)j / 16.0f);
    const float freq = (float)s * inv_freq;
    const float c  = cosf(freq);
    const float sn = sinf(freq);
    const float base = (2.0f * j + 0.4f * 32.0f) / (1.4f * 32.0f);
    const float p    = ((float)s - (float)(S / 2)) / 512.0f;
    const float sc   = powf(base, p);

    const size_t off = (size_t)bs * DMODEL + h * 64 + 2 * j;

    const float q0 = bf2f(q[off]), q1 = bf2f(q[off + 1]);
    q[off]     = f2bf((q0 * c - q1 * sn) * sc);
    q[off + 1] = f2bf((q1 * c + q0 * sn) * sc);

    const float isc = 1.0f / sc;
    const float k0 = bf2f(k[off]), k1 = bf2f(k[off + 1]);
    k[off]     = f2bf((k0 * c - k1 * sn) * isc);
    k[off + 1] = f2bf((k1 * c + k0 * sn) * isc);
}

// ---------------------------------------------------------------------------
// Transpose V per (b,h): vb[b*S+s][h*64+d] -> vt[(b*16+h)*64+d][s]
// ---------------------------------------------------------------------------
__global__ __launch_bounds__(256) void transpose_v_kernel(
    const __bf16* __restrict__ vb, __bf16* __restrict__ vt)
{
    __shared__ __bf16 tile[64][72];
    const int stile = blockIdx.x;   // 0..31
    const int h = blockIdx.y, b = blockIdx.z;
    const int t = threadIdx.x;
    #pragma unroll
    for (int p = 0; p < 2; ++p) {
        const int ci = p * 256 + t;
        const int r = ci >> 3, c8 = (ci & 7) * 8;   // r = s_loc, c8 = d base
        *reinterpret_cast<bf16x8*>(&tile[r][c8]) =
            *reinterpret_cast<const bf16x8*>(
                &vb[(size_t)(b * S + stile * 64 + r) * DMODEL + h * 64 + c8]);
    }
    __syncthreads();
    #pragma unroll
    for (int p = 0; p < 2; ++p) {
        const int ci = p * 256 + t;
        const int d = ci >> 3, s8 = (ci & 7) * 8;
        bf16x8 o;
        #pragma unroll
        for (int w = 0; w < 8; ++w) o[w] = tile[s8 + w][d];
        *reinterpret_cast<bf16x8*>(
            &vt[((size_t)(b * 16 + h) * 64 + d) * 2048 + stile * 64 + s8]) = o;
    }
}

// ---------------------------------------------------------------------------
// Retention via MFMA. q-tile = 128 rows, 4 waves x 32 rows. K/V tiles of 64.
// Job jb per (b,h): jb<16 -> st=jb, j-tiles [0, min(2st+1,15)] -> ret;
//                   jb>=16 -> st=jb-8 (8..15), j-tiles [16, 2st+1] -> ret2.
// No atomics: ret2 holds the second partial for rows s>=1024; GN fuses add.
// S^T = mfma(K,Q) so P writes are packed b64 transpose-on-write.
// All LDS tiles 128B rows with XOR swizzle (byte ^= (row&7)<<4).
// T14: next tile's K/V global loads issued into regs before the MFMA cluster.
// ---------------------------------------------------------------------------
__global__ __launch_bounds__(256) void retention_mfma_kernel(
    const __bf16* __restrict__ qg, const __bf16* __restrict__ kg,
    const __bf16* __restrict__ vtg, float* __restrict__ ret,
    float* __restrict__ ret2)
{
    __shared__ __bf16 q_lds[128 * 64];
    __shared__ __bf16 k_lds[64 * 64];
    __shared__ __bf16 vt_lds[64 * 64];
    __shared__ __bf16 p_lds[128 * 64];

    const int jb = blockIdx.x, h = blockIdx.y, b = blockIdx.z;
    int st, jlo, jhi;
    if (jb < 16) { st = jb; jlo = 0; jhi = (2 * st + 1 < 15) ? 2 * st + 1 : 15; }
    else         { st = jb - 8; jlo = 16; jhi = 2 * st + 1; }
    const int s0 = st * 128;
    const int t = threadIdx.x, wv = t >> 6, ln = t & 63;
    const int lrow = ln & 15, lk8 = (ln >> 4) * 8;

    const float gamma  = 1.0f - exp2f(-5.0f - (float)h);
    const float l2g    = log2f(gamma);
    const float ginv   = exp2f(-l2g);           // 1/gamma
    const float ginv16 = exp2f(-16.0f * l2g);   // gamma^-16
    const size_t base  = (size_t)b * S * DMODEL + h * 64;       // q,k row-major
    const size_t baset = (size_t)(b * 16 + h) * 64 * 2048;      // vt [d][s]

    // stage q tile 128x64 (swizzled)
    #pragma unroll
    for (int p = 0; p < 4; ++p) {
        const int ci = p * 256 + t;
        const int r = ci >> 3, c8 = (ci & 7) * 8;
        *(bf16x8*)((char*)q_lds + r * 128 + ((c8 * 2) ^ ((r & 7) << 4))) =
            *reinterpret_cast<const bf16x8*>(
                &qg[base + (size_t)(s0 + r) * DMODEL + c8]);
    }

    // staging geometry for 64x64 k/v tiles: 2 chunks of 32 rows
    const int sr = t >> 3, sc8 = (t & 7) * 8;
    const int soff0 = sr * 128 + ((sc8 * 2) ^ ((sr & 7) << 4));
    const int soff1 = (sr + 32) * 128 + ((sc8 * 2) ^ ((sr & 7) << 4));

    bf16x8 kr0, kr1, vr0, vr1;
    {
        const int j0 = jlo * 64;
        kr0 = *reinterpret_cast<const bf16x8*>(
            &kg[base + (size_t)(j0 + sr) * DMODEL + sc8]);
        kr1 = *reinterpret_cast<const bf16x8*>(
            &kg[base + (size_t)(j0 + 32 + sr) * DMODEL + sc8]);
        vr0 = *reinterpret_cast<const bf16x8*>(
            &vtg[baset + (size_t)sr * 2048 + j0 + sc8]);
        vr1 = *reinterpret_cast<const bf16x8*>(
            &vtg[baset + (size_t)(sr + 32) * 2048 + j0 + sc8]);
    }

    f32x4 oacc[2][4] = {};

    for (int jt = jlo; jt <= jhi; ++jt) {
        const int j0 = jt * 64;
        __syncthreads();                    // prev iter's LDS reads done
        *(bf16x8*)((char*)k_lds  + soff0) = kr0;
        *(bf16x8*)((char*)k_lds  + soff1) = kr1;
        *(bf16x8*)((char*)vt_lds + soff0) = vr0;
        *(bf16x8*)((char*)vt_lds + soff1) = vr1;
        __syncthreads();

        // T14: issue next tile's global loads now; they complete under MFMA
        if (jt < jhi) {
            const int j0n = (jt + 1) * 64;
            kr0 = *reinterpret_cast<const bf16x8*>(
                &kg[base + (size_t)(j0n + sr) * DMODEL + sc8]);
            kr1 = *reinterpret_cast<const bf16x8*>(
                &kg[base + (size_t)(j0n + 32 + sr) * DMODEL + sc8]);
            vr0 = *reinterpret_cast<const bf16x8*>(
                &vtg[baset + (size_t)sr * 2048 + j0n + sc8]);
            vr1 = *reinterpret_cast<const bf16x8*>(
                &vtg[baset + (size_t)(sr + 32) * 2048 + j0n + sc8]);
        }

        // QK^T (swapped): sacc[ni][mi], lane holds j=mi*16+(ln>>4)*4+reg,
        // i = wv*32 + ni*16 + (ln&15)
        f32x4 sacc[2][4] = {};
        #pragma unroll
        for (int ks = 0; ks < 2; ++ks) {
            bf16x8 qf[2];
            #pragma unroll
            for (int ni = 0; ni < 2; ++ni) {
                const int qrow = wv * 32 + ni * 16 + lrow;
                qf[ni] = *(const bf16x8*)((char*)q_lds + qrow * 128 +
                    (((ks * 32 + lk8) * 2) ^ ((qrow & 7) << 4)));
            }
            #pragma unroll
            for (int mi = 0; mi < 4; ++mi) {
                const int krow = mi * 16 + lrow;
                const bf16x8 kf = *(const bf16x8*)((char*)k_lds + krow * 128 +
                    (((ks * 32 + lk8) * 2) ^ ((krow & 7) << 4)));
                #pragma unroll
                for (int ni = 0; ni < 2; ++ni)
                    sacc[ni][mi] = __builtin_amdgcn_mfma_f32_16x16x32_bf16(
                        kf, qf[ni], sacc[ni][mi], 0, 0, 0);
            }
        }

        // decay + causal mask, pack P[i][j] as b64
        const int d0 = s0 + wv * 32 + (ln & 15) - (ln >> 4) * 4 - j0;
        const bool diag = (jt >= 2 * st);
        #pragma unroll
        for (int ni = 0; ni < 2; ++ni) {
            float wmi = exp2f((float)(d0 + 16 * ni) * l2g);
            #pragma unroll
            for (int mi = 0; mi < 4; ++mi) {
                float wr = wmi;
                ushort4 pk;
                unsigned short* pkp = (unsigned short*)&pk;
                #pragma unroll
                for (int reg = 0; reg < 4; ++reg) {
                    float wgt = wr;
                    if (diag && (d0 + 16 * ni - 16 * mi - reg) < 0) wgt = 0.0f;
                    const __bf16 pb = f2bf(sacc[ni][mi][reg] * wgt);
                    pkp[reg] = *(const unsigned short*)&pb;
                    wr *= ginv;
                }
                const int prow = wv * 32 + ni * 16 + (ln & 15);
                const int jb8 = mi * 16 + (ln >> 4) * 4;
                *(ushort4*)((char*)p_lds + prow * 128 +
                            ((jb8 * 2) ^ ((prow & 7) << 4))) = pk;
                wmi *= ginv16;
            }
        }

        // PV: oacc[ni][nd] += P(32x64) @ V(64x64); P rows wave-private
        #pragma unroll
        for (int ks = 0; ks < 2; ++ks) {
            bf16x8 vf[4];
            #pragma unroll
            for (int nd = 0; nd < 4; ++nd) {
                const int vrow = nd * 16 + lrow;
                vf[nd] = *(const bf16x8*)((char*)vt_lds + vrow * 128 +
                    (((ks * 32 + lk8) * 2) ^ ((vrow & 7) << 4)));
            }
            #pragma unroll
            for (int ni = 0; ni < 2; ++ni) {
                const int prow = wv * 32 + ni * 16 + lrow;
                const bf16x8 pf = *(const bf16x8*)((char*)p_lds + prow * 128 +
                    (((ks * 32 + lk8) * 2) ^ ((prow & 7) << 4)));
                #pragma unroll
                for (int nd = 0; nd < 4; ++nd)
                    oacc[ni][nd] = __builtin_amdgcn_mfma_f32_16x16x32_bf16(
                        pf, vf[nd], oacc[ni][nd], 0, 0, 0);
            }
        }
    }

    // scale by closed-form normalizer and store (no atomics)
    const float sc5h = exp2f(5.0f + (float)h);
    #pragma unroll
    for (int ni = 0; ni < 2; ++ni) {
        #pragma unroll
        for (int reg = 0; reg < 4; ++reg) {
            const int i = s0 + wv * 32 + ni * 16 + (ln >> 4) * 4 + reg;
            const float omg = 1.0f - exp2f((float)(i + 1) * l2g);
            const float invn = rsqrtf(omg * sc5h);
            if (jb < 16) {
                #pragma unroll
                for (int nd = 0; nd < 4; ++nd)
                    ret[base + (size_t)i * DMODEL + nd * 16 + (ln & 15)] =
                        oacc[ni][nd][reg] * invn;
            } else {
                const size_t o2 = ((size_t)b * 1024 + (i - 1024)) * 1024 + h * 64;
                #pragma unroll
                for (int nd = 0; nd < 4; ++nd)
                    ret2[o2 + nd * 16 + (ln & 15)] = oacc[ni][nd][reg] * invn;
            }
        }
    }
}

// ---------------------------------------------------------------------------
// GroupNorm stats, 2 stages. Stage 1 fuses the ret+ret2 partial add.
// ---------------------------------------------------------------------------
__global__ __launch_bounds__(256) void gn_stats1_kernel(
    const float* __restrict__ ret, const float* __restrict__ ret2,
    float* __restrict__ part)
{
    const int sl = blockIdx.x;          // 0..15 slice of 128 rows
    const int bh = blockIdx.y;          // 0..31
    const int b = bh >> 4, h = bh & 15;
    const size_t rowbase = ((size_t)b * S + sl * 128) * DMODEL + h * 64;
    const size_t rowbase2 = ((size_t)b * 1024 + sl * 128 - 1024) * DMODEL + h * 64;
    float sum = 0.0f, sq = 0.0f;
    #pragma unroll
    for (int it = 0; it < 8; ++it) {
        const int idx = it * 256 + threadIdx.x;  // float4 index
        const int row = idx >> 4;
        const int c4 = (idx & 15) * 4;
        float4 v = *reinterpret_cast<const float4*>(
            &ret[rowbase + (size_t)row * DMODEL + c4]);
        if (sl >= 8) {
            const float4 v2 = *reinterpret_cast<const float4*>(
                &ret2[rowbase2 + (size_t)row * DMODEL + c4]);
            v.x += v2.x; v.y += v2.y; v.z += v2.z; v.w += v2.w;
        }
        sum += v.x + v.y + v.z + v.w;
        sq  += v.x * v.x + v.y * v.y + v.z * v.z + v.w * v.w;
    }
    #pragma unroll
    for (int o = 32; o > 0; o >>= 1) {
        sum += __shfl_down(sum, o, 64);
        sq  += __shfl_down(sq, o, 64);
    }
    __shared__ float rs[4], rq[4];
    const int wid = threadIdx.x >> 6, lane = threadIdx.x & 63;
    if (lane == 0) { rs[wid] = sum; rq[wid] = sq; }
    __syncthreads();
    if (threadIdx.x == 0) {
        part[(bh * 16 + sl) * 2 + 0] = rs[0] + rs[1] + rs[2] + rs[3];
        part[(bh * 16 + sl) * 2 + 1] = rq[0] + rq[1] + rq[2] + rq[3];
    }
}

__global__ __launch_bounds__(64) void gn_stats2_kernel(const float* __restrict__ part,
                                                       float* __restrict__ stats)
{
    const int bh = threadIdx.x;
    if (bh < 32) {
        float s = 0.0f, q2 = 0.0f;
        for (int i = 0; i < 16; ++i) {
            s  += part[(bh * 16 + i) * 2 + 0];
            q2 += part[(bh * 16 + i) * 2 + 1];
        }
        const float inv_n = 1.0f / (float)(S * 64);
        const float mean = s * inv_n;
        const float var  = q2 * inv_n - mean * mean;
        stats[bh * 2 + 0] = mean;
        stats[bh * 2 + 1] = rsqrtf(var + 1e-5f);
    }
}

// ---------------------------------------------------------------------------
// y = ((ret[+ret2] - mean) * rstd * gn_w[h] + gn_b[h]) * silu(g), bf16 out.
// ---------------------------------------------------------------------------
__global__ __launch_bounds__(256) void gn_apply_kernel(
    const float* __restrict__ ret, const float* __restrict__ ret2,
    const __bf16* __restrict__ g, __bf16* __restrict__ y,
    const float* __restrict__ stats,
    const float* __restrict__ gnw, const float* __restrict__ gnb)
{
    const size_t p = (size_t)blockIdx.x * 256 + threadIdx.x;  // group of 8
    const size_t el = p * 8;
    const int col = (int)(el & (DMODEL - 1));
    const int s   = (int)((el >> 10) & 2047);
    const int h   = col >> 6;
    const int b   = (int)(el >> 21);              // S*DMODEL = 2^21
    const int bh  = b * H + h;
    const float mean = stats[bh * 2 + 0];
    const float w    = stats[bh * 2 + 1] * gnw[h];
    const float bb   = gnb[h];

    float4 r0 = reinterpret_cast<const float4*>(ret)[2 * p];
    float4 r1 = reinterpret_cast<const float4*>(ret)[2 * p + 1];
    if (s >= 1024) {
        const size_t q2 = ((size_t)b * 1024 + (s - 1024)) * 1024 + col;
        const float4 a0 = *reinterpret_cast<const float4*>(&ret2[q2]);
        const float4 a1 = *reinterpret_cast<const float4*>(&ret2[q2 + 4]);
        r0.x += a0.x; r0.y += a0.y; r0.z += a0.z; r0.w += a0.w;
        r1.x += a1.x; r1.y += a1.y; r1.z += a1.z; r1.w += a1.w;
    }
    const bf16x8 gv = reinterpret_cast<const bf16x8*>(g)[p];
    bf16x8 o;
    o[0] = f2bf(((r0.x - mean) * w + bb) * silu(bf2f(gv[0])));
    o[1] = f2bf(((r0.y - mean) * w + bb) * silu(bf2f(gv[1])));
    o[2] = f2bf(((r0.z - mean) * w + bb) * silu(bf2f(gv[2])));
    o[3] = f2bf(((r0.w - mean) * w + bb) * silu(bf2f(gv[3])));
    o[4] = f2bf(((r1.x - mean) * w + bb) * silu(bf2f(gv[4])));
    o[5] = f2bf(((r1.y - mean) * w + bb) * silu(bf2f(gv[5])));
    o[6] = f2bf(((r1.z - mean) * w + bb) * silu(bf2f(gv[6])));
    o[7] = f2bf(((r1.w - mean) * w + bb) * silu(bf2f(gv[7])));
    reinterpret_cast<bf16x8*>(y)[p] = o;
}

// ---------------------------------------------------------------------------
extern "C" void kernel_launch(void* const* d_in, const int* in_sizes, int n_in,
                              void* d_out, int out_size, void* d_ws, size_t ws_size,
                              hipStream_t stream)
{
    const float* x   = (const float*)d_in[0];
    const float* Wq  = (const float*)d_in[1];
    const float* bq  = (const float*)d_in[2];
    const float* Wk  = (const float*)d_in[3];
    const float* bk  = (const float*)d_in[4];
    const float* Wv  = (const float*)d_in[5];
    const float* bv  = (const float*)d_in[6];
    const float* Wg  = (const float*)d_in[7];
    const float* bg  = (const float*)d_in[8];
    const float* Wo  = (const float*)d_in[9];
    const float* bo  = (const float*)d_in[10];
    const float* gnw = (const float*)d_in[11];
    const float* gnb = (const float*)d_in[12];
    float* out = (float*)d_out;

    // workspace layout
    char* w = (char*)d_ws;
    __bf16* xb      = (__bf16*)w;               w += MAT * 2;            // 8.4MB
    __bf16* wqkvg_t = (__bf16*)w;               w += MAT * 2;            // 8.4MB
    __bf16* wo_t    = (__bf16*)w;               w += (size_t)DMODEL * DMODEL * 2;
    float*  bqkvg   = (float*)w;                w += 4096 * 4;
    __bf16* qb      = (__bf16*)w;               w += MAT * 2;
    __bf16* kb      = (__bf16*)w;               w += MAT * 2;
    __bf16* vb      = (__bf16*)w;               w += MAT * 2;
    __bf16* gb      = (__bf16*)w;               w += MAT * 2;
    float*  ret     = (float*)w;                w += MAT * 4;            // 16.8MB
    __bf16* yb      = (__bf16*)w;               w += MAT * 2;
    float*  part    = (float*)w;                w += 512 * 2 * 4;
    float*  stats   = (float*)w;                w += 64 * 4;
    // aliases over dead prep buffers:
    __bf16* vt   = xb;                 // xb dead after QKVG GEMM
    float*  ret2 = (float*)wqkvg_t;    // wqkvg_t dead after QKVG GEMM (8.4MB fits)

    // allow 128 KiB dynamic LDS for the 8-phase GEMM (idempotent)
    static_cast<void>(hipFuncSetAttribute(
        reinterpret_cast<const void*>(gemm_qkvg_8ph),
        hipFuncAttributeMaxDynamicSharedMemorySize, 131072));

    // 1) prep
    cvt_x_kernel<<<2048, 256, 0, stream>>>(x, xb);
    {
        dim3 grid(32, 32, 5);
        transpose_w_kernel<<<grid, 256, 0, stream>>>(Wq, Wk, Wv, Wg, Wo,
                                                     wqkvg_t, wo_t);
    }
    pack_bias_kernel<<<16, 256, 0, stream>>>(bq, bk, bv, bg, bqkvg);

    // 2) fused QKVG projection GEMM (4096 x 4096 x 1024), 8-phase 256^2
    gemm_qkvg_8ph<<<256, 512, 131072, stream>>>(
        xb, wqkvg_t, bqkvg, qb, kb, vb, gb);

    // 3) rotary xpos + V transpose (vt overwrites xb — safe, GEMM is done)
    rotary_bf16_kernel<<<B * S, 256, 0, stream>>>(qb, kb);
    {
        dim3 grid(32, 16, 2);
        transpose_v_kernel<<<grid, 256, 0, stream>>>(vb, vt);
    }

    // 4) retention (MFMA, 128-row q tiles, split-j, no atomics)
    {
        dim3 grid(24, 16, 2);
        retention_mfma_kernel<<<grid, 256, 0, stream>>>(qb, kb, vt, ret, ret2);
    }

    // 5) group norm + silu gate (fuses ret+ret2)
    {
        dim3 grid(16, 32);
        gn_stats1_kernel<<<grid, 256, 0, stream>>>(ret, ret2, part);
    }
    gn_stats2_kernel<<<1, 64, 0, stream>>>(part, stats);
    gn_apply_kernel<<<2048, 256, 0, stream>>>(ret, ret2, gb, yb, stats, gnw, gnb);

    // 6) output GEMM (4096 x 1024 x 1024), f32 out
    {
        dim3 grid(8, 32);
        gemm_mfma_kernel<<<grid, 256, 0, stream>>>(
            yb, wo_t, bo, out, M_TOT, DMODEL, DMODEL);
    }
}

// Round 6
// 139.694 us; speedup vs baseline: 1.4925x; 1.0967x over previous
//
#include <hip/hip_runtime.h>
#include <math.h>

constexpr int B = 2;
constexpr int S = 2048;
constexpr int DMODEL = 1024;
constexpr int H = 16;
constexpr int M_TOT = B * S;                     // 4096
constexpr size_t MAT = (size_t)B * S * DMODEL;   // 4,194,304 elements

typedef __attribute__((ext_vector_type(8))) __bf16 bf16x8;
typedef __attribute__((ext_vector_type(4))) float f32x4;

#define GLOAD16(g, l) __builtin_amdgcn_global_load_lds( \
    (const __attribute__((address_space(1))) void*)(g), \
    (__attribute__((address_space(3))) void*)(l), 16, 0, 0)

__device__ __forceinline__ float bf2f(__bf16 v) { return (float)v; }
__device__ __forceinline__ __bf16 f2bf(float v) { return (__bf16)v; }
__device__ __forceinline__ float silu(float z) { return z / (1.0f + expf(-z)); }

// ---------------------------------------------------------------------------
// Prep: x fp32 -> bf16 (8 elems / thread)
// ---------------------------------------------------------------------------
__global__ __launch_bounds__(256) void cvt_x_kernel(const float* __restrict__ x,
                                                    __bf16* __restrict__ xb)
{
    const size_t p = (size_t)blockIdx.x * 256 + threadIdx.x;  // group of 8
    const float4 a = reinterpret_cast<const float4*>(x)[2 * p];
    const float4 b = reinterpret_cast<const float4*>(x)[2 * p + 1];
    bf16x8 o;
    o[0] = f2bf(a.x); o[1] = f2bf(a.y); o[2] = f2bf(a.z); o[3] = f2bf(a.w);
    o[4] = f2bf(b.x); o[5] = f2bf(b.y); o[6] = f2bf(b.z); o[7] = f2bf(b.w);
    reinterpret_cast<bf16x8*>(xb)[p] = o;
}

// ---------------------------------------------------------------------------
// Prep: transpose + convert weights. z = 0..3 -> Wq,Wk,Wv,Wg into wqkvg_t
// (row n_global = z*1024 + n, col k). z = 4 -> Wo into wo_t.
// ---------------------------------------------------------------------------
__global__ __launch_bounds__(256) void transpose_w_kernel(
    const float* Wq, const float* Wk, const float* Wv, const float* Wg,
    const float* Wo, __bf16* __restrict__ wqkvg_t, __bf16* __restrict__ wo_t)
{
    __shared__ float tile[32][33];
    const int z = blockIdx.z;
    const float* W = (z == 0) ? Wq : (z == 1) ? Wk : (z == 2) ? Wv
                    : (z == 3) ? Wg : Wo;
    const int n0 = blockIdx.x * 32, k0 = blockIdx.y * 32;
    const int tx = threadIdx.x & 31, ty = threadIdx.x >> 5;  // 32 x 8

    #pragma unroll
    for (int i = 0; i < 32; i += 8)
        tile[ty + i][tx] = W[(size_t)(k0 + ty + i) * DMODEL + n0 + tx];
    __syncthreads();
    #pragma unroll
    for (int i = 0; i < 32; i += 8) {
        const int n = n0 + ty + i, kk = k0 + tx;
        const __bf16 val = f2bf(tile[tx][ty + i]);
        if (z < 4) wqkvg_t[((size_t)z * 1024 + n) * DMODEL + kk] = val;
        else       wo_t[(size_t)n * DMODEL + kk] = val;
    }
}

__global__ __launch_bounds__(256) void pack_bias_kernel(
    const float* bq, const float* bk, const float* bv, const float* bg,
    float* __restrict__ bqkvg)
{
    const int i = blockIdx.x * 256 + threadIdx.x;  // 0..4095
    const float* src = ((i >> 10) == 0) ? bq : ((i >> 10) == 1) ? bk
                      : ((i >> 10) == 2) ? bv : bg;
    bqkvg[i] = src[i & 1023];
}

// ---------------------------------------------------------------------------
// Swizzled LDS layout for 64B (BK=32 bf16) rows.
// Physical slot = logical slot ^ ((row>>1)&3): bank-quad = 4(row&1) +
// (s ^ ((row>>1)&3)) -> 8 distinct quads per 8 rows -> 2 lanes/bank = free.
// Applied on BOTH the pre-swizzled global source and the frag read.
// ---------------------------------------------------------------------------
__device__ __forceinline__ bf16x8 ldsfrag(const char* base, int row, int kbyte)
{
    return *(const bf16x8*)(base + row * 64 + (kbyte ^ (((row >> 1) & 3) << 4)));
}

// 256-row panel stage (512 threads): 2 x global_load_lds per thread.
__device__ __forceinline__ void stage_panel(const __bf16* __restrict__ src,
                                            int srow0, int k0, char* bufbase,
                                            int tid, int wv)
{
    #pragma unroll
    for (int j = 0; j < 2; ++j) {
        const int r  = j * 128 + (tid >> 2);
        const int cb = ((tid & 3) * 16) ^ (((r >> 1) & 3) << 4);
        GLOAD16((const char*)(src + ((size_t)(srow0 + r) << 10) + k0) + cb,
                bufbase + j * 8192 + wv * 1024);
    }
}

// 128-row panel stage (256 threads): 2 x global_load_lds per thread.
__device__ __forceinline__ void stage_panel128(const __bf16* __restrict__ src,
                                               int srow0, int k0, char* bufbase,
                                               int tid, int wv)
{
    #pragma unroll
    for (int j = 0; j < 2; ++j) {
        const int r  = j * 64 + (tid >> 2);
        const int cb = ((tid & 3) * 16) ^ (((r >> 1) & 3) << 4);
        GLOAD16((const char*)(src + ((size_t)(srow0 + r) << 10) + k0) + cb,
                bufbase + j * 4096 + wv * 1024);
    }
}

// ---------------------------------------------------------------------------
// 8-wave 256x256 QKVG GEMM (K=1024), 1 barrier per K-tile, ring-4 LDS,
// counted vmcnt(8), compiler-managed lgkmcnt, setprio around 32-MFMA cluster.
// ---------------------------------------------------------------------------
__global__ __launch_bounds__(512) void gemm_qkvg_8ph(
    const __bf16* __restrict__ A, const __bf16* __restrict__ Bt,
    const float* __restrict__ bias,
    __bf16* o0, __bf16* o1, __bf16* o2, __bf16* o3)
{
    extern __shared__ char lds[];   // 131072 B: A ring 4x16KB, B ring 4x16KB
    constexpr int NTK = 32;         // 1024 / 32

    const int tid = threadIdx.x, wv = tid >> 6, ln = tid & 63;
    const int wm = wv >> 2, wn = wv & 3;

    // XCD-aware swizzle (nwg=256, 8 XCDs, cpx=32) then 16x16 block grid
    int bid = blockIdx.x;
    bid = (bid & 7) * 32 + (bid >> 3);
    const int bx = bid & 15, by = bid >> 4;
    const int row0 = by * 256, col0 = bx * 256;

    const int lrow = ln & 15;
    const int kb   = (ln >> 4) * 16;   // logical k byte offset within 64B row

    f32x4 acc[8][4] = {};

    // prologue: stage K-tiles 0,1,2 (12 loads in flight)
    #pragma unroll
    for (int tt = 0; tt < 3; ++tt) {
        stage_panel(A,  row0, tt * 32, lds + tt * 16384, tid, wv);
        stage_panel(Bt, col0, tt * 32, lds + 65536 + tt * 16384, tid, wv);
    }
    asm volatile("s_waitcnt vmcnt(8)" ::: "memory");   // publish tile 0
    __builtin_amdgcn_s_barrier();
    __builtin_amdgcn_sched_barrier(0);

    for (int t = 0; t < NTK; ++t) {
        const char* ab = lds + (t & 3) * 16384;
        const char* bb = lds + 65536 + (t & 3) * 16384;
        bf16x8 af[8], bf[4];
        #pragma unroll
        for (int mf = 0; mf < 8; ++mf)
            af[mf] = ldsfrag(ab, wm * 128 + mf * 16 + lrow, kb);
        #pragma unroll
        for (int nf = 0; nf < 4; ++nf)
            bf[nf] = ldsfrag(bb, wn * 64 + nf * 16 + lrow, kb);

        // prefetch K-tile t+3 into ring slot (t+3)&3 (readers of that slot
        // finished at the end-of-(t-1) barrier)
        if (t + 3 < NTK) {
            stage_panel(A,  row0, (t + 3) * 32,
                        lds + ((t + 3) & 3) * 16384, tid, wv);
            stage_panel(Bt, col0, (t + 3) * 32,
                        lds + 65536 + ((t + 3) & 3) * 16384, tid, wv);
        }

        __builtin_amdgcn_s_setprio(1);
        #pragma unroll
        for (int mf = 0; mf < 8; ++mf)
            #pragma unroll
            for (int nf = 0; nf < 4; ++nf)
                acc[mf][nf] = __builtin_amdgcn_mfma_f32_16x16x32_bf16(
                    af[mf], bf[nf], acc[mf][nf], 0, 0, 0);
        __builtin_amdgcn_s_setprio(0);

        // publish K-tile t+1 (counted; drains only in the tail)
        if (t <= NTK - 4)
            asm volatile("s_waitcnt vmcnt(8)" ::: "memory");
        else if (t == NTK - 3)
            asm volatile("s_waitcnt vmcnt(4)" ::: "memory");
        else if (t == NTK - 2)
            asm volatile("s_waitcnt vmcnt(0)" ::: "memory");
        __builtin_amdgcn_s_barrier();
        __builtin_amdgcn_sched_barrier(0);
    }

    // epilogue: bias add + bf16 store; block maps to exactly one output
    const int sel = col0 >> 10;
    __bf16* outp = (sel == 0) ? o0 : (sel == 1) ? o1 : (sel == 2) ? o2 : o3;
    const int cb0 = col0 & 1023;
    #pragma unroll
    for (int mf = 0; mf < 8; ++mf) {
        #pragma unroll
        for (int nf = 0; nf < 4; ++nf) {
            const int cl = cb0 + wn * 64 + nf * 16 + (ln & 15);
            const float bs = bias[col0 + wn * 64 + nf * 16 + (ln & 15)];
            #pragma unroll
            for (int reg = 0; reg < 4; ++reg) {
                const int r = row0 + wm * 128 + mf * 16 + (ln >> 4) * 4 + reg;
                outp[(size_t)r * 1024 + cl] = f2bf(acc[mf][nf][reg] + bs);
            }
        }
    }
}

// ---------------------------------------------------------------------------
// Wo GEMM: 4-wave 128x128 tile, same 1-barrier ring-4 schedule, f32 out.
// Grid (8, 32) = 256 blocks, 64KB static LDS -> 2 blocks/CU.
// ---------------------------------------------------------------------------
__global__ __launch_bounds__(256) void gemm_wo_kernel(
    const __bf16* __restrict__ A, const __bf16* __restrict__ Bt,
    const float* __restrict__ bias, float* __restrict__ fout)
{
    __shared__ char lds[65536];     // A ring 4x8KB @0, B ring 4x8KB @32768
    constexpr int NTK = 32;         // K=1024 / 32

    const int tid = threadIdx.x, wv = tid >> 6, ln = tid & 63;
    const int row0 = blockIdx.y * 128, col0 = blockIdx.x * 128;
    const int wr = (wv >> 1) * 64, wc = (wv & 1) * 64;
    const int lrow = ln & 15, kb = (ln >> 4) * 16;

    f32x4 acc[4][4] = {};

    #pragma unroll
    for (int tt = 0; tt < 3; ++tt) {
        stage_panel128(A,  row0, tt * 32, lds + tt * 8192, tid, wv);
        stage_panel128(Bt, col0, tt * 32, lds + 32768 + tt * 8192, tid, wv);
    }
    asm volatile("s_waitcnt vmcnt(8)" ::: "memory");
    __builtin_amdgcn_s_barrier();
    __builtin_amdgcn_sched_barrier(0);

    for (int t = 0; t < NTK; ++t) {
        const char* ab = lds + (t & 3) * 8192;
        const char* bb = lds + 32768 + (t & 3) * 8192;
        bf16x8 af[4], bf[4];
        #pragma unroll
        for (int mi = 0; mi < 4; ++mi)
            af[mi] = ldsfrag(ab, wr + mi * 16 + lrow, kb);
        #pragma unroll
        for (int ni = 0; ni < 4; ++ni)
            bf[ni] = ldsfrag(bb, wc + ni * 16 + lrow, kb);

        if (t + 3 < NTK) {
            stage_panel128(A,  row0, (t + 3) * 32,
                           lds + ((t + 3) & 3) * 8192, tid, wv);
            stage_panel128(Bt, col0, (t + 3) * 32,
                           lds + 32768 + ((t + 3) & 3) * 8192, tid, wv);
        }

        __builtin_amdgcn_s_setprio(1);
        #pragma unroll
        for (int mi = 0; mi < 4; ++mi)
            #pragma unroll
            for (int ni = 0; ni < 4; ++ni)
                acc[mi][ni] = __builtin_amdgcn_mfma_f32_16x16x32_bf16(
                    af[mi], bf[ni], acc[mi][ni], 0, 0, 0);
        __builtin_amdgcn_s_setprio(0);

        if (t <= NTK - 4)
            asm volatile("s_waitcnt vmcnt(8)" ::: "memory");
        else if (t == NTK - 3)
            asm volatile("s_waitcnt vmcnt(4)" ::: "memory");
        else if (t == NTK - 2)
            asm volatile("s_waitcnt vmcnt(0)" ::: "memory");
        __builtin_amdgcn_s_barrier();
        __builtin_amdgcn_sched_barrier(0);
    }

    #pragma unroll
    for (int mi = 0; mi < 4; ++mi) {
        #pragma unroll
        for (int ni = 0; ni < 4; ++ni) {
            const int c = col0 + wc + ni * 16 + (ln & 15);
            const float bs = bias[c];
            #pragma unroll
            for (int reg = 0; reg < 4; ++reg) {
                const int r = row0 + wr + mi * 16 + (ln >> 4) * 4 + reg;
                fout[(size_t)r * DMODEL + c] = acc[mi][ni][reg] + bs;
            }
        }
    }
}

// ---------------------------------------------------------------------------
// xPos rotary on bf16 q (scale) and k (1/scale), in place.
// ---------------------------------------------------------------------------
__global__ __launch_bounds__(256) void rotary_bf16_kernel(__bf16* __restrict__ q,
                                                          __bf16* __restrict__ k)
{
    const int bs = blockIdx.x;
    const int s  = bs & (S - 1);
    const int h  = threadIdx.x >> 4;
    const int j  = threadIdx.x & 15;

    const float inv_freq = powf(10000.0f, -(float)j / 16.0f);
    const float freq = (float)s * inv_freq;
    const float c  = cosf(freq);
    const float sn = sinf(freq);
    const float base = (2.0f * j + 0.4f * 32.0f) / (1.4f * 32.0f);
    const float p    = ((float)s - (float)(S / 2)) / 512.0f;
    const float sc   = powf(base, p);

    const size_t off = (size_t)bs * DMODEL + h * 64 + 2 * j;

    const float q0 = bf2f(q[off]), q1 = bf2f(q[off + 1]);
    q[off]     = f2bf((q0 * c - q1 * sn) * sc);
    q[off + 1] = f2bf((q1 * c + q0 * sn) * sc);

    const float isc = 1.0f / sc;
    const float k0 = bf2f(k[off]), k1 = bf2f(k[off + 1]);
    k[off]     = f2bf((k0 * c - k1 * sn) * isc);
    k[off + 1] = f2bf((k1 * c + k0 * sn) * isc);
}

// ---------------------------------------------------------------------------
// Transpose V per (b,h): vb[b*S+s][h*64+d] -> vt[(b*16+h)*64+d][s]
// ---------------------------------------------------------------------------
__global__ __launch_bounds__(256) void transpose_v_kernel(
    const __bf16* __restrict__ vb, __bf16* __restrict__ vt)
{
    __shared__ __bf16 tile[64][72];
    const int stile = blockIdx.x;   // 0..31
    const int h = blockIdx.y, b = blockIdx.z;
    const int t = threadIdx.x;
    #pragma unroll
    for (int p = 0; p < 2; ++p) {
        const int ci = p * 256 + t;
        const int r = ci >> 3, c8 = (ci & 7) * 8;   // r = s_loc, c8 = d base
        *reinterpret_cast<bf16x8*>(&tile[r][c8]) =
            *reinterpret_cast<const bf16x8*>(
                &vb[(size_t)(b * S + stile * 64 + r) * DMODEL + h * 64 + c8]);
    }
    __syncthreads();
    #pragma unroll
    for (int p = 0; p < 2; ++p) {
        const int ci = p * 256 + t;
        const int d = ci >> 3, s8 = (ci & 7) * 8;
        bf16x8 o;
        #pragma unroll
        for (int w = 0; w < 8; ++w) o[w] = tile[s8 + w][d];
        *reinterpret_cast<bf16x8*>(
            &vt[((size_t)(b * 16 + h) * 64 + d) * 2048 + stile * 64 + s8]) = o;
    }
}

// ---------------------------------------------------------------------------
// Retention via MFMA. q-tile = 128 rows, 4 waves x 32 rows. K/V tiles of 64.
// Job jb per (b,h): jb<16 -> st=jb, j-tiles [0, min(2st+1,15)] -> ret;
//                   jb>=16 -> st=jb-8 (8..15), j-tiles [16, 2st+1] -> ret2.
// No atomics: ret2 holds the second partial for rows s>=1024; GN fuses add.
// S^T = mfma(K,Q) so P writes are packed b64 transpose-on-write.
// All LDS tiles 128B rows with XOR swizzle (byte ^= (row&7)<<4).
// T14: next tile's K/V global loads issued into regs before the MFMA cluster.
// ---------------------------------------------------------------------------
__global__ __launch_bounds__(256) void retention_mfma_kernel(
    const __bf16* __restrict__ qg, const __bf16* __restrict__ kg,
    const __bf16* __restrict__ vtg, float* __restrict__ ret,
    float* __restrict__ ret2)
{
    __shared__ __bf16 q_lds[128 * 64];
    __shared__ __bf16 k_lds[64 * 64];
    __shared__ __bf16 vt_lds[64 * 64];
    __shared__ __bf16 p_lds[128 * 64];

    const int jb = blockIdx.x, h = blockIdx.y, b = blockIdx.z;
    int st, jlo, jhi;
    if (jb < 16) { st = jb; jlo = 0; jhi = (2 * st + 1 < 15) ? 2 * st + 1 : 15; }
    else         { st = jb - 8; jlo = 16; jhi = 2 * st + 1; }
    const int s0 = st * 128;
    const int t = threadIdx.x, wv = t >> 6, ln = t & 63;
    const int lrow = ln & 15, lk8 = (ln >> 4) * 8;

    const float gamma  = 1.0f - exp2f(-5.0f - (float)h);
    const float l2g    = log2f(gamma);
    const float ginv   = exp2f(-l2g);           // 1/gamma
    const float ginv16 = exp2f(-16.0f * l2g);   // gamma^-16
    const size_t base  = (size_t)b * S * DMODEL + h * 64;       // q,k row-major
    const size_t baset = (size_t)(b * 16 + h) * 64 * 2048;      // vt [d][s]

    // stage q tile 128x64 (swizzled)
    #pragma unroll
    for (int p = 0; p < 4; ++p) {
        const int ci = p * 256 + t;
        const int r = ci >> 3, c8 = (ci & 7) * 8;
        *(bf16x8*)((char*)q_lds + r * 128 + ((c8 * 2) ^ ((r & 7) << 4))) =
            *reinterpret_cast<const bf16x8*>(
                &qg[base + (size_t)(s0 + r) * DMODEL + c8]);
    }

    // staging geometry for 64x64 k/v tiles: 2 chunks of 32 rows
    const int sr = t >> 3, sc8 = (t & 7) * 8;
    const int soff0 = sr * 128 + ((sc8 * 2) ^ ((sr & 7) << 4));
    const int soff1 = (sr + 32) * 128 + ((sc8 * 2) ^ ((sr & 7) << 4));

    bf16x8 kr0, kr1, vr0, vr1;
    {
        const int j0 = jlo * 64;
        kr0 = *reinterpret_cast<const bf16x8*>(
            &kg[base + (size_t)(j0 + sr) * DMODEL + sc8]);
        kr1 = *reinterpret_cast<const bf16x8*>(
            &kg[base + (size_t)(j0 + 32 + sr) * DMODEL + sc8]);
        vr0 = *reinterpret_cast<const bf16x8*>(
            &vtg[baset + (size_t)sr * 2048 + j0 + sc8]);
        vr1 = *reinterpret_cast<const bf16x8*>(
            &vtg[baset + (size_t)(sr + 32) * 2048 + j0 + sc8]);
    }

    f32x4 oacc[2][4] = {};

    for (int jt = jlo; jt <= jhi; ++jt) {
        const int j0 = jt * 64;
        __syncthreads();                    // prev iter's LDS reads done
        *(bf16x8*)((char*)k_lds  + soff0) = kr0;
        *(bf16x8*)((char*)k_lds  + soff1) = kr1;
        *(bf16x8*)((char*)vt_lds + soff0) = vr0;
        *(bf16x8*)((char*)vt_lds + soff1) = vr1;
        __syncthreads();

        // T14: issue next tile's global loads now; they complete under MFMA
        if (jt < jhi) {
            const int j0n = (jt + 1) * 64;
            kr0 = *reinterpret_cast<const bf16x8*>(
                &kg[base + (size_t)(j0n + sr) * DMODEL + sc8]);
            kr1 = *reinterpret_cast<const bf16x8*>(
                &kg[base + (size_t)(j0n + 32 + sr) * DMODEL + sc8]);
            vr0 = *reinterpret_cast<const bf16x8*>(
                &vtg[baset + (size_t)sr * 2048 + j0n + sc8]);
            vr1 = *reinterpret_cast<const bf16x8*>(
                &vtg[baset + (size_t)(sr + 32) * 2048 + j0n + sc8]);
        }

        // QK^T (swapped): sacc[ni][mi], lane holds j=mi*16+(ln>>4)*4+reg,
        // i = wv*32 + ni*16 + (ln&15)
        f32x4 sacc[2][4] = {};
        #pragma unroll
        for (int ks = 0; ks < 2; ++ks) {
            bf16x8 qf[2];
            #pragma unroll
            for (int ni = 0; ni < 2; ++ni) {
                const int qrow = wv * 32 + ni * 16 + lrow;
                qf[ni] = *(const bf16x8*)((char*)q_lds + qrow * 128 +
                    (((ks * 32 + lk8) * 2) ^ ((qrow & 7) << 4)));
            }
            #pragma unroll
            for (int mi = 0; mi < 4; ++mi) {
                const int krow = mi * 16 + lrow;
                const bf16x8 kf = *(const bf16x8*)((char*)k_lds + krow * 128 +
                    (((ks * 32 + lk8) * 2) ^ ((krow & 7) << 4)));
                #pragma unroll
                for (int ni = 0; ni < 2; ++ni)
                    sacc[ni][mi] = __builtin_amdgcn_mfma_f32_16x16x32_bf16(
                        kf, qf[ni], sacc[ni][mi], 0, 0, 0);
            }
        }

        // decay + causal mask, pack P[i][j] as b64
        const int d0 = s0 + wv * 32 + (ln & 15) - (ln >> 4) * 4 - j0;
        const bool diag = (jt >= 2 * st);
        #pragma unroll
        for (int ni = 0; ni < 2; ++ni) {
            float wmi = exp2f((float)(d0 + 16 * ni) * l2g);
            #pragma unroll
            for (int mi = 0; mi < 4; ++mi) {
                float wr = wmi;
                ushort4 pk;
                unsigned short* pkp = (unsigned short*)&pk;
                #pragma unroll
                for (int reg = 0; reg < 4; ++reg) {
                    float wgt = wr;
                    if (diag && (d0 + 16 * ni - 16 * mi - reg) < 0) wgt = 0.0f;
                    const __bf16 pb = f2bf(sacc[ni][mi][reg] * wgt);
                    pkp[reg] = *(const unsigned short*)&pb;
                    wr *= ginv;
                }
                const int prow = wv * 32 + ni * 16 + (ln & 15);
                const int jb8 = mi * 16 + (ln >> 4) * 4;
                *(ushort4*)((char*)p_lds + prow * 128 +
                            ((jb8 * 2) ^ ((prow & 7) << 4))) = pk;
                wmi *= ginv16;
            }
        }

        // PV: oacc[ni][nd] += P(32x64) @ V(64x64); P rows wave-private
        #pragma unroll
        for (int ks = 0; ks < 2; ++ks) {
            bf16x8 vf[4];
            #pragma unroll
            for (int nd = 0; nd < 4; ++nd) {
                const int vrow = nd * 16 + lrow;
                vf[nd] = *(const bf16x8*)((char*)vt_lds + vrow * 128 +
                    (((ks * 32 + lk8) * 2) ^ ((vrow & 7) << 4)));
            }
            #pragma unroll
            for (int ni = 0; ni < 2; ++ni) {
                const int prow = wv * 32 + ni * 16 + lrow;
                const bf16x8 pf = *(const bf16x8*)((char*)p_lds + prow * 128 +
                    (((ks * 32 + lk8) * 2) ^ ((prow & 7) << 4)));
                #pragma unroll
                for (int nd = 0; nd < 4; ++nd)
                    oacc[ni][nd] = __builtin_amdgcn_mfma_f32_16x16x32_bf16(
                        pf, vf[nd], oacc[ni][nd], 0, 0, 0);
            }
        }
    }

    // scale by closed-form normalizer and store (no atomics)
    const float sc5h = exp2f(5.0f + (float)h);
    #pragma unroll
    for (int ni = 0; ni < 2; ++ni) {
        #pragma unroll
        for (int reg = 0; reg < 4; ++reg) {
            const int i = s0 + wv * 32 + ni * 16 + (ln >> 4) * 4 + reg;
            const float omg = 1.0f - exp2f((float)(i + 1) * l2g);
            const float invn = rsqrtf(omg * sc5h);
            if (jb < 16) {
                #pragma unroll
                for (int nd = 0; nd < 4; ++nd)
                    ret[base + (size_t)i * DMODEL + nd * 16 + (ln & 15)] =
                        oacc[ni][nd][reg] * invn;
            } else {
                const size_t o2 = ((size_t)b * 1024 + (i - 1024)) * 1024 + h * 64;
                #pragma unroll
                for (int nd = 0; nd < 4; ++nd)
                    ret2[o2 + nd * 16 + (ln & 15)] = oacc[ni][nd][reg] * invn;
            }
        }
    }
}

// ---------------------------------------------------------------------------
// GroupNorm stats, 2 stages. Stage 1 fuses the ret+ret2 partial add.
// ---------------------------------------------------------------------------
__global__ __launch_bounds__(256) void gn_stats1_kernel(
    const float* __restrict__ ret, const float* __restrict__ ret2,
    float* __restrict__ part)
{
    const int sl = blockIdx.x;          // 0..15 slice of 128 rows
    const int bh = blockIdx.y;          // 0..31
    const int b = bh >> 4, h = bh & 15;
    const size_t rowbase = ((size_t)b * S + sl * 128) * DMODEL + h * 64;
    const size_t rowbase2 = ((size_t)b * 1024 + sl * 128 - 1024) * DMODEL + h * 64;
    float sum = 0.0f, sq = 0.0f;
    #pragma unroll
    for (int it = 0; it < 8; ++it) {
        const int idx = it * 256 + threadIdx.x;  // float4 index
        const int row = idx >> 4;
        const int c4 = (idx & 15) * 4;
        float4 v = *reinterpret_cast<const float4*>(
            &ret[rowbase + (size_t)row * DMODEL + c4]);
        if (sl >= 8) {
            const float4 v2 = *reinterpret_cast<const float4*>(
                &ret2[rowbase2 + (size_t)row * DMODEL + c4]);
            v.x += v2.x; v.y += v2.y; v.z += v2.z; v.w += v2.w;
        }
        sum += v.x + v.y + v.z + v.w;
        sq  += v.x * v.x + v.y * v.y + v.z * v.z + v.w * v.w;
    }
    #pragma unroll
    for (int o = 32; o > 0; o >>= 1) {
        sum += __shfl_down(sum, o, 64);
        sq  += __shfl_down(sq, o, 64);
    }
    __shared__ float rs[4], rq[4];
    const int wid = threadIdx.x >> 6, lane = threadIdx.x & 63;
    if (lane == 0) { rs[wid] = sum; rq[wid] = sq; }
    __syncthreads();
    if (threadIdx.x == 0) {
        part[(bh * 16 + sl) * 2 + 0] = rs[0] + rs[1] + rs[2] + rs[3];
        part[(bh * 16 + sl) * 2 + 1] = rq[0] + rq[1] + rq[2] + rq[3];
    }
}

__global__ __launch_bounds__(64) void gn_stats2_kernel(const float* __restrict__ part,
                                                       float* __restrict__ stats)
{
    const int bh = threadIdx.x;
    if (bh < 32) {
        float s = 0.0f, q2 = 0.0f;
        for (int i = 0; i < 16; ++i) {
            s  += part[(bh * 16 + i) * 2 + 0];
            q2 += part[(bh * 16 + i) * 2 + 1];
        }
        const float inv_n = 1.0f / (float)(S * 64);
        const float mean = s * inv_n;
        const float var  = q2 * inv_n - mean * mean;
        stats[bh * 2 + 0] = mean;
        stats[bh * 2 + 1] = rsqrtf(var + 1e-5f);
    }
}

// ---------------------------------------------------------------------------
// y = ((ret[+ret2] - mean) * rstd * gn_w[h] + gn_b[h]) * silu(g), bf16 out.
// ---------------------------------------------------------------------------
__global__ __launch_bounds__(256) void gn_apply_kernel(
    const float* __restrict__ ret, const float* __restrict__ ret2,
    const __bf16* __restrict__ g, __bf16* __restrict__ y,
    const float* __restrict__ stats,
    const float* __restrict__ gnw, const float* __restrict__ gnb)
{
    const size_t p = (size_t)blockIdx.x * 256 + threadIdx.x;  // group of 8
    const size_t el = p * 8;
    const int col = (int)(el & (DMODEL - 1));
    const int s   = (int)((el >> 10) & 2047);
    const int h   = col >> 6;
    const int b   = (int)(el >> 21);              // S*DMODEL = 2^21
    const int bh  = b * H + h;
    const float mean = stats[bh * 2 + 0];
    const float w    = stats[bh * 2 + 1] * gnw[h];
    const float bb   = gnb[h];

    float4 r0 = reinterpret_cast<const float4*>(ret)[2 * p];
    float4 r1 = reinterpret_cast<const float4*>(ret)[2 * p + 1];
    if (s >= 1024) {
        const size_t q2 = ((size_t)b * 1024 + (s - 1024)) * 1024 + col;
        const float4 a0 = *reinterpret_cast<const float4*>(&ret2[q2]);
        const float4 a1 = *reinterpret_cast<const float4*>(&ret2[q2 + 4]);
        r0.x += a0.x; r0.y += a0.y; r0.z += a0.z; r0.w += a0.w;
        r1.x += a1.x; r1.y += a1.y; r1.z += a1.z; r1.w += a1.w;
    }
    const bf16x8 gv = reinterpret_cast<const bf16x8*>(g)[p];
    bf16x8 o;
    o[0] = f2bf(((r0.x - mean) * w + bb) * silu(bf2f(gv[0])));
    o[1] = f2bf(((r0.y - mean) * w + bb) * silu(bf2f(gv[1])));
    o[2] = f2bf(((r0.z - mean) * w + bb) * silu(bf2f(gv[2])));
    o[3] = f2bf(((r0.w - mean) * w + bb) * silu(bf2f(gv[3])));
    o[4] = f2bf(((r1.x - mean) * w + bb) * silu(bf2f(gv[4])));
    o[5] = f2bf(((r1.y - mean) * w + bb) * silu(bf2f(gv[5])));
    o[6] = f2bf(((r1.z - mean) * w + bb) * silu(bf2f(gv[6])));
    o[7] = f2bf(((r1.w - mean) * w + bb) * silu(bf2f(gv[7])));
    reinterpret_cast<bf16x8*>(y)[p] = o;
}

// ---------------------------------------------------------------------------
extern "C" void kernel_launch(void* const* d_in, const int* in_sizes, int n_in,
                              void* d_out, int out_size, void* d_ws, size_t ws_size,
                              hipStream_t stream)
{
    const float* x   = (const float*)d_in[0];
    const float* Wq  = (const float*)d_in[1];
    const float* bq  = (const float*)d_in[2];
    const float* Wk  = (const float*)d_in[3];
    const float* bk  = (const float*)d_in[4];
    const float* Wv  = (const float*)d_in[5];
    const float* bv  = (const float*)d_in[6];
    const float* Wg  = (const float*)d_in[7];
    const float* bg  = (const float*)d_in[8];
    const float* Wo  = (const float*)d_in[9];
    const float* bo  = (const float*)d_in[10];
    const float* gnw = (const float*)d_in[11];
    const float* gnb = (const float*)d_in[12];
    float* out = (float*)d_out;

    // workspace layout
    char* w = (char*)d_ws;
    __bf16* xb      = (__bf16*)w;               w += MAT * 2;            // 8.4MB
    __bf16* wqkvg_t = (__bf16*)w;               w += MAT * 2;            // 8.4MB
    __bf16* wo_t    = (__bf16*)w;               w += (size_t)DMODEL * DMODEL * 2;
    float*  bqkvg   = (float*)w;                w += 4096 * 4;
    __bf16* qb      = (__bf16*)w;               w += MAT * 2;
    __bf16* kb      = (__bf16*)w;               w += MAT * 2;
    __bf16* vb      = (__bf16*)w;               w += MAT * 2;
    __bf16* gb      = (__bf16*)w;               w += MAT * 2;
    float*  ret     = (float*)w;                w += MAT * 4;            // 16.8MB
    __bf16* yb      = (__bf16*)w;               w += MAT * 2;
    float*  part    = (float*)w;                w += 512 * 2 * 4;
    float*  stats   = (float*)w;                w += 64 * 4;
    // aliases over dead prep buffers:
    __bf16* vt   = xb;                 // xb dead after QKVG GEMM
    float*  ret2 = (float*)wqkvg_t;    // wqkvg_t dead after QKVG GEMM (8.4MB fits)

    // allow 128 KiB dynamic LDS for the QKVG GEMM (idempotent)
    static_cast<void>(hipFuncSetAttribute(
        reinterpret_cast<const void*>(gemm_qkvg_8ph),
        hipFuncAttributeMaxDynamicSharedMemorySize, 131072));

    // 1) prep
    cvt_x_kernel<<<2048, 256, 0, stream>>>(x, xb);
    {
        dim3 grid(32, 32, 5);
        transpose_w_kernel<<<grid, 256, 0, stream>>>(Wq, Wk, Wv, Wg, Wo,
                                                     wqkvg_t, wo_t);
    }
    pack_bias_kernel<<<16, 256, 0, stream>>>(bq, bk, bv, bg, bqkvg);

    // 2) fused QKVG projection GEMM (4096 x 4096 x 1024)
    gemm_qkvg_8ph<<<256, 512, 131072, stream>>>(
        xb, wqkvg_t, bqkvg, qb, kb, vb, gb);

    // 3) rotary xpos + V transpose (vt overwrites xb — safe, GEMM is done)
    rotary_bf16_kernel<<<B * S, 256, 0, stream>>>(qb, kb);
    {
        dim3 grid(32, 16, 2);
        transpose_v_kernel<<<grid, 256, 0, stream>>>(vb, vt);
    }

    // 4) retention (MFMA, 128-row q tiles, split-j, no atomics)
    {
        dim3 grid(24, 16, 2);
        retention_mfma_kernel<<<grid, 256, 0, stream>>>(qb, kb, vt, ret, ret2);
    }

    // 5) group norm + silu gate (fuses ret+ret2)
    {
        dim3 grid(16, 32);
        gn_stats1_kernel<<<grid, 256, 0, stream>>>(ret, ret2, part);
    }
    gn_stats2_kernel<<<1, 64, 0, stream>>>(part, stats);
    gn_apply_kernel<<<2048, 256, 0, stream>>>(ret, ret2, gb, yb, stats, gnw, gnb);

    // 6) output GEMM (4096 x 1024 x 1024), f32 out
    {
        dim3 grid(8, 32);
        gemm_wo_kernel<<<grid, 256, 0, stream>>>(yb, wo_t, bo, out);
    }
}

// Round 7
// 126.611 us; speedup vs baseline: 1.6468x; 1.1033x over previous
//
#include <hip/hip_runtime.h>
#include <math.h>

constexpr int B = 2;
constexpr int S = 2048;
constexpr int DMODEL = 1024;
constexpr int H = 16;
constexpr int M_TOT = B * S;                     // 4096
constexpr size_t MAT = (size_t)B * S * DMODEL;   // 4,194,304 elements

typedef __attribute__((ext_vector_type(8))) __bf16 bf16x8;
typedef __attribute__((ext_vector_type(4))) float f32x4;

#define GLOAD16(g, l) __builtin_amdgcn_global_load_lds( \
    (const __attribute__((address_space(1))) void*)(g), \
    (__attribute__((address_space(3))) void*)(l), 16, 0, 0)

__device__ __forceinline__ float bf2f(__bf16 v) { return (float)v; }
__device__ __forceinline__ __bf16 f2bf(float v) { return (__bf16)v; }
__device__ __forceinline__ float silu(float z) { return z / (1.0f + expf(-z)); }

// ---------------------------------------------------------------------------
// Prep: x fp32 -> bf16 (8 elems / thread)
// ---------------------------------------------------------------------------
__global__ __launch_bounds__(256) void cvt_x_kernel(const float* __restrict__ x,
                                                    __bf16* __restrict__ xb)
{
    const size_t p = (size_t)blockIdx.x * 256 + threadIdx.x;  // group of 8
    const float4 a = reinterpret_cast<const float4*>(x)[2 * p];
    const float4 b = reinterpret_cast<const float4*>(x)[2 * p + 1];
    bf16x8 o;
    o[0] = f2bf(a.x); o[1] = f2bf(a.y); o[2] = f2bf(a.z); o[3] = f2bf(a.w);
    o[4] = f2bf(b.x); o[5] = f2bf(b.y); o[6] = f2bf(b.z); o[7] = f2bf(b.w);
    reinterpret_cast<bf16x8*>(xb)[p] = o;
}

// ---------------------------------------------------------------------------
// Prep: transpose + convert weights. z = 0..3 -> Wq,Wk,Wv,Wg into wqkvg_t
// (row n_global = z*1024 + n, col k). z = 4 -> Wo into wo_t.
// ---------------------------------------------------------------------------
__global__ __launch_bounds__(256) void transpose_w_kernel(
    const float* Wq, const float* Wk, const float* Wv, const float* Wg,
    const float* Wo, __bf16* __restrict__ wqkvg_t, __bf16* __restrict__ wo_t)
{
    __shared__ float tile[32][33];
    const int z = blockIdx.z;
    const float* W = (z == 0) ? Wq : (z == 1) ? Wk : (z == 2) ? Wv
                    : (z == 3) ? Wg : Wo;
    const int n0 = blockIdx.x * 32, k0 = blockIdx.y * 32;
    const int tx = threadIdx.x & 31, ty = threadIdx.x >> 5;  // 32 x 8

    #pragma unroll
    for (int i = 0; i < 32; i += 8)
        tile[ty + i][tx] = W[(size_t)(k0 + ty + i) * DMODEL + n0 + tx];
    __syncthreads();
    #pragma unroll
    for (int i = 0; i < 32; i += 8) {
        const int n = n0 + ty + i, kk = k0 + tx;
        const __bf16 val = f2bf(tile[tx][ty + i]);
        if (z < 4) wqkvg_t[((size_t)z * 1024 + n) * DMODEL + kk] = val;
        else       wo_t[(size_t)n * DMODEL + kk] = val;
    }
}

__global__ __launch_bounds__(256) void pack_bias_kernel(
    const float* bq, const float* bk, const float* bv, const float* bg,
    float* __restrict__ bqkvg)
{
    const int i = blockIdx.x * 256 + threadIdx.x;  // 0..4095
    const float* src = ((i >> 10) == 0) ? bq : ((i >> 10) == 1) ? bk
                      : ((i >> 10) == 2) ? bv : bg;
    bqkvg[i] = src[i & 1023];
}

// ---------------------------------------------------------------------------
// Swizzled LDS layout for 64B (BK=32 bf16) rows.
// Physical slot = logical slot ^ ((row>>1)&3).
// ---------------------------------------------------------------------------
__device__ __forceinline__ bf16x8 ldsfrag(const char* base, int row, int kbyte)
{
    return *(const bf16x8*)(base + row * 64 + (kbyte ^ (((row >> 1) & 3) << 4)));
}

// 256-row panel stage (512 threads): 2 x global_load_lds per thread.
__device__ __forceinline__ void stage_panel(const __bf16* __restrict__ src,
                                            int srow0, int k0, char* bufbase,
                                            int tid, int wv)
{
    #pragma unroll
    for (int j = 0; j < 2; ++j) {
        const int r  = j * 128 + (tid >> 2);
        const int cb = ((tid & 3) * 16) ^ (((r >> 1) & 3) << 4);
        GLOAD16((const char*)(src + ((size_t)(srow0 + r) << 10) + k0) + cb,
                bufbase + j * 8192 + wv * 1024);
    }
}

// 128-row panel stage (256 threads): 2 x global_load_lds per thread.
__device__ __forceinline__ void stage_panel128(const __bf16* __restrict__ src,
                                               int srow0, int k0, char* bufbase,
                                               int tid, int wv)
{
    #pragma unroll
    for (int j = 0; j < 2; ++j) {
        const int r  = j * 64 + (tid >> 2);
        const int cb = ((tid & 3) * 16) ^ (((r >> 1) & 3) << 4);
        GLOAD16((const char*)(src + ((size_t)(srow0 + r) << 10) + k0) + cb,
                bufbase + j * 4096 + wv * 1024);
    }
}

// ---------------------------------------------------------------------------
// 8-wave 256x256 QKVG GEMM (K=1024), 1 barrier per K-tile, ring-4 LDS,
// counted vmcnt(8), setprio around 32-MFMA cluster.
// ---------------------------------------------------------------------------
__global__ __launch_bounds__(512) void gemm_qkvg_8ph(
    const __bf16* __restrict__ A, const __bf16* __restrict__ Bt,
    const float* __restrict__ bias,
    __bf16* o0, __bf16* o1, __bf16* o2, __bf16* o3)
{
    extern __shared__ char lds[];   // 131072 B: A ring 4x16KB, B ring 4x16KB
    constexpr int NTK = 32;         // 1024 / 32

    const int tid = threadIdx.x, wv = tid >> 6, ln = tid & 63;
    const int wm = wv >> 2, wn = wv & 3;

    int bid = blockIdx.x;
    bid = (bid & 7) * 32 + (bid >> 3);
    const int bx = bid & 15, by = bid >> 4;
    const int row0 = by * 256, col0 = bx * 256;

    const int lrow = ln & 15;
    const int kb   = (ln >> 4) * 16;

    f32x4 acc[8][4] = {};

    #pragma unroll
    for (int tt = 0; tt < 3; ++tt) {
        stage_panel(A,  row0, tt * 32, lds + tt * 16384, tid, wv);
        stage_panel(Bt, col0, tt * 32, lds + 65536 + tt * 16384, tid, wv);
    }
    asm volatile("s_waitcnt vmcnt(8)" ::: "memory");
    __builtin_amdgcn_s_barrier();
    __builtin_amdgcn_sched_barrier(0);

    for (int t = 0; t < NTK; ++t) {
        const char* ab = lds + (t & 3) * 16384;
        const char* bb = lds + 65536 + (t & 3) * 16384;
        bf16x8 af[8], bf[4];
        #pragma unroll
        for (int mf = 0; mf < 8; ++mf)
            af[mf] = ldsfrag(ab, wm * 128 + mf * 16 + lrow, kb);
        #pragma unroll
        for (int nf = 0; nf < 4; ++nf)
            bf[nf] = ldsfrag(bb, wn * 64 + nf * 16 + lrow, kb);

        if (t + 3 < NTK) {
            stage_panel(A,  row0, (t + 3) * 32,
                        lds + ((t + 3) & 3) * 16384, tid, wv);
            stage_panel(Bt, col0, (t + 3) * 32,
                        lds + 65536 + ((t + 3) & 3) * 16384, tid, wv);
        }

        __builtin_amdgcn_s_setprio(1);
        #pragma unroll
        for (int mf = 0; mf < 8; ++mf)
            #pragma unroll
            for (int nf = 0; nf < 4; ++nf)
                acc[mf][nf] = __builtin_amdgcn_mfma_f32_16x16x32_bf16(
                    af[mf], bf[nf], acc[mf][nf], 0, 0, 0);
        __builtin_amdgcn_s_setprio(0);

        if (t <= NTK - 4)
            asm volatile("s_waitcnt vmcnt(8)" ::: "memory");
        else if (t == NTK - 3)
            asm volatile("s_waitcnt vmcnt(4)" ::: "memory");
        else if (t == NTK - 2)
            asm volatile("s_waitcnt vmcnt(0)" ::: "memory");
        __builtin_amdgcn_s_barrier();
        __builtin_amdgcn_sched_barrier(0);
    }

    const int sel = col0 >> 10;
    __bf16* outp = (sel == 0) ? o0 : (sel == 1) ? o1 : (sel == 2) ? o2 : o3;
    const int cb0 = col0 & 1023;
    #pragma unroll
    for (int mf = 0; mf < 8; ++mf) {
        #pragma unroll
        for (int nf = 0; nf < 4; ++nf) {
            const int cl = cb0 + wn * 64 + nf * 16 + (ln & 15);
            const float bs = bias[col0 + wn * 64 + nf * 16 + (ln & 15)];
            #pragma unroll
            for (int reg = 0; reg < 4; ++reg) {
                const int r = row0 + wm * 128 + mf * 16 + (ln >> 4) * 4 + reg;
                outp[(size_t)r * 1024 + cl] = f2bf(acc[mf][nf][reg] + bs);
            }
        }
    }
}

// ---------------------------------------------------------------------------
// Wo GEMM: 4-wave 128x128 tile, same 1-barrier ring-4 schedule, f32 out.
// ---------------------------------------------------------------------------
__global__ __launch_bounds__(256) void gemm_wo_kernel(
    const __bf16* __restrict__ A, const __bf16* __restrict__ Bt,
    const float* __restrict__ bias, float* __restrict__ fout)
{
    __shared__ char lds[65536];
    constexpr int NTK = 32;

    const int tid = threadIdx.x, wv = tid >> 6, ln = tid & 63;
    const int row0 = blockIdx.y * 128, col0 = blockIdx.x * 128;
    const int wr = (wv >> 1) * 64, wc = (wv & 1) * 64;
    const int lrow = ln & 15, kb = (ln >> 4) * 16;

    f32x4 acc[4][4] = {};

    #pragma unroll
    for (int tt = 0; tt < 3; ++tt) {
        stage_panel128(A,  row0, tt * 32, lds + tt * 8192, tid, wv);
        stage_panel128(Bt, col0, tt * 32, lds + 32768 + tt * 8192, tid, wv);
    }
    asm volatile("s_waitcnt vmcnt(8)" ::: "memory");
    __builtin_amdgcn_s_barrier();
    __builtin_amdgcn_sched_barrier(0);

    for (int t = 0; t < NTK; ++t) {
        const char* ab = lds + (t & 3) * 8192;
        const char* bb = lds + 32768 + (t & 3) * 8192;
        bf16x8 af[4], bf[4];
        #pragma unroll
        for (int mi = 0; mi < 4; ++mi)
            af[mi] = ldsfrag(ab, wr + mi * 16 + lrow, kb);
        #pragma unroll
        for (int ni = 0; ni < 4; ++ni)
            bf[ni] = ldsfrag(bb, wc + ni * 16 + lrow, kb);

        if (t + 3 < NTK) {
            stage_panel128(A,  row0, (t + 3) * 32,
                           lds + ((t + 3) & 3) * 8192, tid, wv);
            stage_panel128(Bt, col0, (t + 3) * 32,
                           lds + 32768 + ((t + 3) & 3) * 8192, tid, wv);
        }

        __builtin_amdgcn_s_setprio(1);
        #pragma unroll
        for (int mi = 0; mi < 4; ++mi)
            #pragma unroll
            for (int ni = 0; ni < 4; ++ni)
                acc[mi][ni] = __builtin_amdgcn_mfma_f32_16x16x32_bf16(
                    af[mi], bf[ni], acc[mi][ni], 0, 0, 0);
        __builtin_amdgcn_s_setprio(0);

        if (t <= NTK - 4)
            asm volatile("s_waitcnt vmcnt(8)" ::: "memory");
        else if (t == NTK - 3)
            asm volatile("s_waitcnt vmcnt(4)" ::: "memory");
        else if (t == NTK - 2)
            asm volatile("s_waitcnt vmcnt(0)" ::: "memory");
        __builtin_amdgcn_s_barrier();
        __builtin_amdgcn_sched_barrier(0);
    }

    #pragma unroll
    for (int mi = 0; mi < 4; ++mi) {
        #pragma unroll
        for (int ni = 0; ni < 4; ++ni) {
            const int c = col0 + wc + ni * 16 + (ln & 15);
            const float bs = bias[c];
            #pragma unroll
            for (int reg = 0; reg < 4; ++reg) {
                const int r = row0 + wr + mi * 16 + (ln >> 4) * 4 + reg;
                fout[(size_t)r * DMODEL + c] = acc[mi][ni][reg] + bs;
            }
        }
    }
}

// ---------------------------------------------------------------------------
// xPos rotary + decay-weight fold, in place.
// q <- rot(q)*sc * gamma^(sloc+1)   (all 64 dims get the gamma weight)
// k <- rot(k)/sc * gamma^(63-sloc)
// Thread (h, j): rot pair (2j, 2j+1) and pass-through pair (32+2j, 33+2j).
// ---------------------------------------------------------------------------
__global__ __launch_bounds__(256) void rotary_bf16_kernel(__bf16* __restrict__ q,
                                                          __bf16* __restrict__ k)
{
    const int bs = blockIdx.x;
    const int s  = bs & (S - 1);
    const int h  = threadIdx.x >> 4;
    const int j  = threadIdx.x & 15;
    const int sloc = s & 63;

    const float gamma = 1.0f - exp2f(-5.0f - (float)h);
    const float l2g   = log2f(gamma);
    const float wq = exp2f((float)(sloc + 1) * l2g);
    const float wk = exp2f((float)(63 - sloc) * l2g);

    const float inv_freq = powf(10000.0f, -(float)j / 16.0f);
    const float freq = (float)s * inv_freq;
    const float c  = cosf(freq);
    const float sn = sinf(freq);
    const float base = (2.0f * j + 0.4f * 32.0f) / (1.4f * 32.0f);
    const float p    = ((float)s - (float)(S / 2)) / 512.0f;
    const float sc   = powf(base, p);

    const size_t off = (size_t)bs * DMODEL + h * 64 + 2 * j;

    const float q0 = bf2f(q[off]), q1 = bf2f(q[off + 1]);
    q[off]     = f2bf((q0 * c - q1 * sn) * sc * wq);
    q[off + 1] = f2bf((q1 * c + q0 * sn) * sc * wq);

    const float isc = 1.0f / sc;
    const float k0 = bf2f(k[off]), k1 = bf2f(k[off + 1]);
    k[off]     = f2bf((k0 * c - k1 * sn) * isc * wk);
    k[off + 1] = f2bf((k1 * c + k0 * sn) * isc * wk);

    // pass-through dims 32..63: decay weight only
    const size_t off2 = off + 32;
    q[off2]     = f2bf(bf2f(q[off2])     * wq);
    q[off2 + 1] = f2bf(bf2f(q[off2 + 1]) * wq);
    k[off2]     = f2bf(bf2f(k[off2])     * wk);
    k[off2 + 1] = f2bf(bf2f(k[off2 + 1]) * wk);
}

// ---------------------------------------------------------------------------
// Transpose K-hat / V per (b,h): src[b*S+s][h*64+d] -> dst[(b*16+h)*64+d][s]
// z = b*2 + which (which: 0 = v->vt, 1 = k->kt).
// ---------------------------------------------------------------------------
__global__ __launch_bounds__(256) void transpose_kv_kernel(
    const __bf16* __restrict__ kb, const __bf16* __restrict__ vb,
    __bf16* __restrict__ kt, __bf16* __restrict__ vt)
{
    __shared__ __bf16 tile[64][72];
    const int stile = blockIdx.x;   // 0..31
    const int h = blockIdx.y;
    const int b = blockIdx.z >> 1, which = blockIdx.z & 1;
    const __bf16* src = which ? kb : vb;
    __bf16* dst = which ? kt : vt;
    const int t = threadIdx.x;
    #pragma unroll
    for (int p = 0; p < 2; ++p) {
        const int ci = p * 256 + t;
        const int r = ci >> 3, c8 = (ci & 7) * 8;
        *reinterpret_cast<bf16x8*>(&tile[r][c8]) =
            *reinterpret_cast<const bf16x8*>(
                &src[(size_t)(b * S + stile * 64 + r) * DMODEL + h * 64 + c8]);
    }
    __syncthreads();
    #pragma unroll
    for (int p = 0; p < 2; ++p) {
        const int ci = p * 256 + t;
        const int d = ci >> 3, s8 = (ci & 7) * 8;
        bf16x8 o;
        #pragma unroll
        for (int w = 0; w < 8; ++w) o[w] = tile[s8 + w][d];
        *reinterpret_cast<bf16x8*>(
            &dst[((size_t)(b * 16 + h) * 64 + d) * 2048 + stile * 64 + s8]) = o;
    }
}

// ---------------------------------------------------------------------------
// k1: per-chunk outer product U^T_c[dv][dk] = V_c^T @ K-hat_c
// (K-hat rows already weighted by gamma^(63-jloc) via rotary).
// Grid (32 chunks, 16 h, 2 b), 256 thr = 4 waves x 16 dv rows.
// ---------------------------------------------------------------------------
__global__ __launch_bounds__(256) void chunk_outer_kernel(
    const __bf16* __restrict__ kt, const __bf16* __restrict__ vt,
    float* __restrict__ U)
{
    __shared__ __bf16 kl[64 * 64];
    __shared__ __bf16 vl[64 * 64];
    const int c = blockIdx.x, h = blockIdx.y, b = blockIdx.z;
    const int bh = b * 16 + h;
    const size_t baset = (size_t)bh * 64 * 2048 + c * 64;
    const int t = threadIdx.x, wv = t >> 6, ln = t & 63;
    const int lrow = ln & 15, lk8 = (ln >> 4) * 8;

    #pragma unroll
    for (int p = 0; p < 2; ++p) {
        const int ci = p * 256 + t;
        const int r = ci >> 3, c8 = (ci & 7) * 8;
        const int off = r * 128 + ((c8 * 2) ^ ((r & 7) << 4));
        *(bf16x8*)((char*)kl + off) =
            *reinterpret_cast<const bf16x8*>(&kt[baset + (size_t)r * 2048 + c8]);
        *(bf16x8*)((char*)vl + off) =
            *reinterpret_cast<const bf16x8*>(&vt[baset + (size_t)r * 2048 + c8]);
    }
    __syncthreads();

    f32x4 uacc[4] = {};
    #pragma unroll
    for (int ks = 0; ks < 2; ++ks) {
        const int arow = wv * 16 + lrow;
        const bf16x8 af = *(const bf16x8*)((char*)vl + arow * 128 +
            (((ks * 32 + lk8) * 2) ^ ((arow & 7) << 4)));
        #pragma unroll
        for (int nf = 0; nf < 4; ++nf) {
            const int brow = nf * 16 + lrow;
            const bf16x8 bf_ = *(const bf16x8*)((char*)kl + brow * 128 +
                (((ks * 32 + lk8) * 2) ^ ((brow & 7) << 4)));
            uacc[nf] = __builtin_amdgcn_mfma_f32_16x16x32_bf16(
                af, bf_, uacc[nf], 0, 0, 0);
        }
    }

    const size_t ub = ((size_t)bh * 32 + c) * 4096;
    #pragma unroll
    for (int nf = 0; nf < 4; ++nf) {
        const int dk = nf * 16 + (ln & 15);
        #pragma unroll
        for (int reg = 0; reg < 4; ++reg) {
            const int dv = wv * 16 + (ln >> 4) * 4 + reg;
            U[ub + dv * 64 + dk] = uacc[nf][reg];
        }
    }
}

// ---------------------------------------------------------------------------
// k2: sequential scan S_c = gamma^64 * S_{c-1} + U_{c-1}, S_0 = 0.
// Writes St[c][dv][dk] (bf16). Grid (4 dv-quarters, 32 bh), 256 thr.
// ---------------------------------------------------------------------------
__global__ __launch_bounds__(256) void chunk_scan_kernel(
    const float* __restrict__ U, __bf16* __restrict__ St)
{
    const int dvq = blockIdx.x, bh = blockIdx.y;
    const int h = bh & 15;
    const float gamma = 1.0f - exp2f(-5.0f - (float)h);
    const float g64 = exp2f(64.0f * log2f(gamma));
    const int t = threadIdx.x;
    const int dk = t & 63;
    const int dv0 = dvq * 16 + (t >> 6) * 4;
    float s0 = 0.f, s1 = 0.f, s2 = 0.f, s3 = 0.f;
    const size_t ub = (size_t)bh * 32 * 4096;
    for (int c = 0; c < 32; ++c) {
        const size_t sb = ub + (size_t)c * 4096;
        St[sb + (dv0 + 0) * 64 + dk] = f2bf(s0);
        St[sb + (dv0 + 1) * 64 + dk] = f2bf(s1);
        St[sb + (dv0 + 2) * 64 + dk] = f2bf(s2);
        St[sb + (dv0 + 3) * 64 + dk] = f2bf(s3);
        s0 = g64 * s0 + U[sb + (dv0 + 0) * 64 + dk];
        s1 = g64 * s1 + U[sb + (dv0 + 1) * 64 + dk];
        s2 = g64 * s2 + U[sb + (dv0 + 2) * 64 + dk];
        s3 = g64 * s3 + U[sb + (dv0 + 3) * 64 + dk];
    }
}

// ---------------------------------------------------------------------------
// k3: per-chunk retention: O = gamma^-64 * (Qhat Khat^T (.) mask) V + Qhat S_c,
// then row-normalize. Grid (32 chunks, 16 h, 2 b), 256 thr = 4 waves x 16 i.
// Qhat/Khat carry the decay weights from rotary. Single ret write, no atomics.
// ---------------------------------------------------------------------------
__global__ __launch_bounds__(256) void retention_chunk_kernel(
    const __bf16* __restrict__ qg, const __bf16* __restrict__ kg,
    const __bf16* __restrict__ vt, const __bf16* __restrict__ St,
    float* __restrict__ ret)
{
    __shared__ __bf16 qh[64 * 64];
    __shared__ __bf16 kh[64 * 64];
    __shared__ __bf16 vl[64 * 64];
    __shared__ __bf16 sl[64 * 64];
    __shared__ __bf16 pl[64 * 64];

    const int c = blockIdx.x, h = blockIdx.y, b = blockIdx.z;
    const int bh = b * 16 + h;
    const int t = threadIdx.x, wv = t >> 6, ln = t & 63;
    const int lrow = ln & 15, lk8 = (ln >> 4) * 8;

    const float gamma = 1.0f - exp2f(-5.0f - (float)h);
    const float l2g   = log2f(gamma);
    const float gm64i = exp2f(-64.0f * l2g);          // gamma^-64
    const size_t rowbase = ((size_t)b * S + c * 64) * DMODEL + h * 64;
    const size_t vtb = (size_t)bh * 64 * 2048 + c * 64;
    const size_t stb = ((size_t)bh * 32 + c) * 4096;

    #pragma unroll
    for (int p = 0; p < 2; ++p) {
        const int ci = p * 256 + t;
        const int r = ci >> 3, c8 = (ci & 7) * 8;
        const int off = r * 128 + ((c8 * 2) ^ ((r & 7) << 4));
        *(bf16x8*)((char*)qh + off) =
            *reinterpret_cast<const bf16x8*>(&qg[rowbase + (size_t)r * DMODEL + c8]);
        *(bf16x8*)((char*)kh + off) =
            *reinterpret_cast<const bf16x8*>(&kg[rowbase + (size_t)r * DMODEL + c8]);
        *(bf16x8*)((char*)vl + off) =
            *reinterpret_cast<const bf16x8*>(&vt[vtb + (size_t)r * 2048 + c8]);
        *(bf16x8*)((char*)sl + off) =
            *reinterpret_cast<const bf16x8*>(&St[stb + r * 64 + c8]);
    }
    __syncthreads();

    // intra scores (swapped): lane holds j = mi*16+(ln>>4)*4+reg, i = wv*16+(ln&15)
    f32x4 sacc[4] = {};
    #pragma unroll
    for (int ks = 0; ks < 2; ++ks) {
        const int qrow = wv * 16 + lrow;
        const bf16x8 qf = *(const bf16x8*)((char*)qh + qrow * 128 +
            (((ks * 32 + lk8) * 2) ^ ((qrow & 7) << 4)));
        #pragma unroll
        for (int mi = 0; mi < 4; ++mi) {
            const int krow = mi * 16 + lrow;
            const bf16x8 kf = *(const bf16x8*)((char*)kh + krow * 128 +
                (((ks * 32 + lk8) * 2) ^ ((krow & 7) << 4)));
            sacc[mi] = __builtin_amdgcn_mfma_f32_16x16x32_bf16(
                kf, qf, sacc[mi], 0, 0, 0);
        }
    }

    // pack P: P[i][j] = gamma^-64 * sacc, causal mask j <= i
    const int iw = wv * 16 + (ln & 15);
    #pragma unroll
    for (int mi = 0; mi < 4; ++mi) {
        ushort4 pk;
        unsigned short* pkp = (unsigned short*)&pk;
        #pragma unroll
        for (int reg = 0; reg < 4; ++reg) {
            const int j = mi * 16 + (ln >> 4) * 4 + reg;
            const float pv = (j <= iw) ? sacc[mi][reg] * gm64i : 0.0f;
            const __bf16 pb = f2bf(pv);
            pkp[reg] = *(const unsigned short*)&pb;
        }
        const int jb8 = mi * 16 + (ln >> 4) * 4;
        *(ushort4*)((char*)pl + iw * 128 + ((jb8 * 2) ^ ((iw & 7) << 4))) = pk;
    }

    // acc = P @ V + Qhat @ S  (both B operands [dv][k] in LDS)
    f32x4 acc[4] = {};
    #pragma unroll
    for (int ks = 0; ks < 2; ++ks) {
        const int prow = wv * 16 + lrow;
        const bf16x8 pf = *(const bf16x8*)((char*)pl + prow * 128 +
            (((ks * 32 + lk8) * 2) ^ ((prow & 7) << 4)));
        const bf16x8 qf2 = *(const bf16x8*)((char*)qh + prow * 128 +
            (((ks * 32 + lk8) * 2) ^ ((prow & 7) << 4)));
        #pragma unroll
        for (int nd = 0; nd < 4; ++nd) {
            const int vrow = nd * 16 + lrow;
            const bf16x8 vf = *(const bf16x8*)((char*)vl + vrow * 128 +
                (((ks * 32 + lk8) * 2) ^ ((vrow & 7) << 4)));
            const bf16x8 sf = *(const bf16x8*)((char*)sl + vrow * 128 +
                (((ks * 32 + lk8) * 2) ^ ((vrow & 7) << 4)));
            acc[nd] = __builtin_amdgcn_mfma_f32_16x16x32_bf16(
                pf, vf, acc[nd], 0, 0, 0);
            acc[nd] = __builtin_amdgcn_mfma_f32_16x16x32_bf16(
                qf2, sf, acc[nd], 0, 0, 0);
        }
    }

    // normalize and store
    const float sc5h = exp2f(5.0f + (float)h);
    #pragma unroll
    for (int reg = 0; reg < 4; ++reg) {
        const int i = c * 64 + wv * 16 + (ln >> 4) * 4 + reg;
        const float omg = 1.0f - exp2f((float)(i + 1) * l2g);
        const float invn = rsqrtf(omg * sc5h);
        #pragma unroll
        for (int nd = 0; nd < 4; ++nd)
            ret[((size_t)b * S + i) * DMODEL + h * 64 + nd * 16 + (ln & 15)] =
                acc[nd][reg] * invn;
    }
}

// ---------------------------------------------------------------------------
// GroupNorm stats, 2 stages.
// ---------------------------------------------------------------------------
__global__ __launch_bounds__(256) void gn_stats1_kernel(
    const float* __restrict__ ret, float* __restrict__ part)
{
    const int sl = blockIdx.x;          // 0..15 slice of 128 rows
    const int bh = blockIdx.y;          // 0..31
    const int b = bh >> 4, h = bh & 15;
    const size_t rowbase = ((size_t)b * S + sl * 128) * DMODEL + h * 64;
    float sum = 0.0f, sq = 0.0f;
    #pragma unroll
    for (int it = 0; it < 8; ++it) {
        const int idx = it * 256 + threadIdx.x;  // float4 index
        const int row = idx >> 4;
        const int c4 = (idx & 15) * 4;
        const float4 v = *reinterpret_cast<const float4*>(
            &ret[rowbase + (size_t)row * DMODEL + c4]);
        sum += v.x + v.y + v.z + v.w;
        sq  += v.x * v.x + v.y * v.y + v.z * v.z + v.w * v.w;
    }
    #pragma unroll
    for (int o = 32; o > 0; o >>= 1) {
        sum += __shfl_down(sum, o, 64);
        sq  += __shfl_down(sq, o, 64);
    }
    __shared__ float rs[4], rq[4];
    const int wid = threadIdx.x >> 6, lane = threadIdx.x & 63;
    if (lane == 0) { rs[wid] = sum; rq[wid] = sq; }
    __syncthreads();
    if (threadIdx.x == 0) {
        part[(bh * 16 + sl) * 2 + 0] = rs[0] + rs[1] + rs[2] + rs[3];
        part[(bh * 16 + sl) * 2 + 1] = rq[0] + rq[1] + rq[2] + rq[3];
    }
}

__global__ __launch_bounds__(64) void gn_stats2_kernel(const float* __restrict__ part,
                                                       float* __restrict__ stats)
{
    const int bh = threadIdx.x;
    if (bh < 32) {
        float s = 0.0f, q2 = 0.0f;
        for (int i = 0; i < 16; ++i) {
            s  += part[(bh * 16 + i) * 2 + 0];
            q2 += part[(bh * 16 + i) * 2 + 1];
        }
        const float inv_n = 1.0f / (float)(S * 64);
        const float mean = s * inv_n;
        const float var  = q2 * inv_n - mean * mean;
        stats[bh * 2 + 0] = mean;
        stats[bh * 2 + 1] = rsqrtf(var + 1e-5f);
    }
}

// ---------------------------------------------------------------------------
// y = ((ret - mean) * rstd * gn_w[h] + gn_b[h]) * silu(g), bf16 out.
// ---------------------------------------------------------------------------
__global__ __launch_bounds__(256) void gn_apply_kernel(
    const float* __restrict__ ret, const __bf16* __restrict__ g,
    __bf16* __restrict__ y, const float* __restrict__ stats,
    const float* __restrict__ gnw, const float* __restrict__ gnb)
{
    const size_t p = (size_t)blockIdx.x * 256 + threadIdx.x;  // group of 8
    const size_t el = p * 8;
    const int col = (int)(el & (DMODEL - 1));
    const int h   = col >> 6;
    const int b   = (int)(el >> 21);              // S*DMODEL = 2^21
    const int bh  = b * H + h;
    const float mean = stats[bh * 2 + 0];
    const float w    = stats[bh * 2 + 1] * gnw[h];
    const float bb   = gnb[h];

    const float4 r0 = reinterpret_cast<const float4*>(ret)[2 * p];
    const float4 r1 = reinterpret_cast<const float4*>(ret)[2 * p + 1];
    const bf16x8 gv = reinterpret_cast<const bf16x8*>(g)[p];
    bf16x8 o;
    o[0] = f2bf(((r0.x - mean) * w + bb) * silu(bf2f(gv[0])));
    o[1] = f2bf(((r0.y - mean) * w + bb) * silu(bf2f(gv[1])));
    o[2] = f2bf(((r0.z - mean) * w + bb) * silu(bf2f(gv[2])));
    o[3] = f2bf(((r0.w - mean) * w + bb) * silu(bf2f(gv[3])));
    o[4] = f2bf(((r1.x - mean) * w + bb) * silu(bf2f(gv[4])));
    o[5] = f2bf(((r1.y - mean) * w + bb) * silu(bf2f(gv[5])));
    o[6] = f2bf(((r1.z - mean) * w + bb) * silu(bf2f(gv[6])));
    o[7] = f2bf(((r1.w - mean) * w + bb) * silu(bf2f(gv[7])));
    reinterpret_cast<bf16x8*>(y)[p] = o;
}

// ---------------------------------------------------------------------------
extern "C" void kernel_launch(void* const* d_in, const int* in_sizes, int n_in,
                              void* d_out, int out_size, void* d_ws, size_t ws_size,
                              hipStream_t stream)
{
    const float* x   = (const float*)d_in[0];
    const float* Wq  = (const float*)d_in[1];
    const float* bq  = (const float*)d_in[2];
    const float* Wk  = (const float*)d_in[3];
    const float* bk  = (const float*)d_in[4];
    const float* Wv  = (const float*)d_in[5];
    const float* bv  = (const float*)d_in[6];
    const float* Wg  = (const float*)d_in[7];
    const float* bg  = (const float*)d_in[8];
    const float* Wo  = (const float*)d_in[9];
    const float* bo  = (const float*)d_in[10];
    const float* gnw = (const float*)d_in[11];
    const float* gnb = (const float*)d_in[12];
    float* out = (float*)d_out;

    // workspace layout
    char* w = (char*)d_ws;
    __bf16* xb      = (__bf16*)w;               w += MAT * 2;            // 8.4MB
    __bf16* wqkvg_t = (__bf16*)w;               w += MAT * 2;            // 8.4MB
    __bf16* wo_t    = (__bf16*)w;               w += (size_t)DMODEL * DMODEL * 2;
    float*  bqkvg   = (float*)w;                w += 4096 * 4;
    __bf16* qb      = (__bf16*)w;               w += MAT * 2;
    __bf16* kb      = (__bf16*)w;               w += MAT * 2;
    __bf16* vb      = (__bf16*)w;               w += MAT * 2;
    __bf16* gb      = (__bf16*)w;               w += MAT * 2;
    float*  ret     = (float*)w;                w += MAT * 4;            // 16.8MB
    __bf16* yb      = (__bf16*)w;               w += MAT * 2;
    float*  part    = (float*)w;                w += 512 * 2 * 4;
    float*  stats   = (float*)w;                w += 64 * 4;
    // aliases over dead buffers:
    __bf16* vt = xb;               // xb dead after QKVG GEMM
    __bf16* kt = yb;               // yb written only later by gn_apply
    float*  U  = ret;              // U consumed by scan before k3 writes ret
    __bf16* St = (__bf16*)wqkvg_t; // wqkvg_t dead after QKVG GEMM (8.4MB)

    // allow 128 KiB dynamic LDS for the QKVG GEMM (idempotent)
    static_cast<void>(hipFuncSetAttribute(
        reinterpret_cast<const void*>(gemm_qkvg_8ph),
        hipFuncAttributeMaxDynamicSharedMemorySize, 131072));

    // 1) prep
    cvt_x_kernel<<<2048, 256, 0, stream>>>(x, xb);
    {
        dim3 grid(32, 32, 5);
        transpose_w_kernel<<<grid, 256, 0, stream>>>(Wq, Wk, Wv, Wg, Wo,
                                                     wqkvg_t, wo_t);
    }
    pack_bias_kernel<<<16, 256, 0, stream>>>(bq, bk, bv, bg, bqkvg);

    // 2) fused QKVG projection GEMM (4096 x 4096 x 1024)
    gemm_qkvg_8ph<<<256, 512, 131072, stream>>>(
        xb, wqkvg_t, bqkvg, qb, kb, vb, gb);

    // 3) rotary xpos + decay-weight fold; transpose K-hat and V
    rotary_bf16_kernel<<<B * S, 256, 0, stream>>>(qb, kb);
    {
        dim3 grid(32, 16, 4);
        transpose_kv_kernel<<<grid, 256, 0, stream>>>(kb, vb, kt, vt);
    }

    // 4) chunked retention: outer products -> scan -> per-chunk retention
    {
        dim3 grid(32, 16, 2);
        chunk_outer_kernel<<<grid, 256, 0, stream>>>(kt, vt, U);
    }
    {
        dim3 grid(4, 32);
        chunk_scan_kernel<<<grid, 256, 0, stream>>>(U, St);
    }
    {
        dim3 grid(32, 16, 2);
        retention_chunk_kernel<<<grid, 256, 0, stream>>>(qb, kb, vt, St, ret);
    }

    // 5) group norm + silu gate
    {
        dim3 grid(16, 32);
        gn_stats1_kernel<<<grid, 256, 0, stream>>>(ret, part);
    }
    gn_stats2_kernel<<<1, 64, 0, stream>>>(part, stats);
    gn_apply_kernel<<<2048, 256, 0, stream>>>(ret, gb, yb, stats, gnw, gnb);

    // 6) output GEMM (4096 x 1024 x 1024), f32 out
    {
        dim3 grid(8, 32);
        gemm_wo_kernel<<<grid, 256, 0, stream>>>(yb, wo_t, bo, out);
    }
}